// Round 10
// baseline (2998.598 us; speedup 1.0000x reference)
//
#include <hip/hip_runtime.h>
#include <hip/hip_bf16.h>
#include <math.h>

#define NB 32
#define CK 512
#define C1 1024
#define CA 80
#define CQ 80
#define CQ2 160
#define TEN 400
#define TDE 2000

static constexpr float TEMP = 0.0005f;

// OUTPUT DTYPE: the reference returns float32 JAX arrays; d_out is float*.
// (R9 probe proved this: bf16 writes at bf16-idx 25.6M landed at float-idx
// 12.8M inside chunk0, producing the long-standing bit-exact 0.0747 error.)

// ---------------------------------------------------------------------------
// Key conv1 (verbatim R6)
// ---------------------------------------------------------------------------
__global__ __launch_bounds__(256) void kconv1_kernel(
    const float* __restrict__ keys, const float* __restrict__ w1,
    const float* __restrict__ b1, float* __restrict__ k1) {
  __shared__ float kLDS[32][66];
  __shared__ float wLDS[64][98];
  const int mtile = blockIdx.x;
  const int b  = blockIdx.y / 7;
  const int tt = blockIdx.y % 7;
  const int t0 = tt * 64;
  const int co0 = mtile * 64;
  const int tid = threadIdx.x;
  const int ty = tid >> 4, tx = tid & 15;
  float acc[4][4] = {};
  for (int ci0 = 0; ci0 < CK; ci0 += 32) {
    for (int idx = tid; idx < 32 * 66; idx += 256) {
      int r = idx / 66, j = idx % 66;
      int t = t0 - 1 + j;
      kLDS[r][j] = (t >= 0 && t < TEN) ? keys[((size_t)b * CK + ci0 + r) * TEN + t] : 0.f;
    }
    for (int idx = tid; idx < 64 * 96; idx += 256) {
      int r = idx / 96, kk = idx % 96;
      wLDS[r][kk] = w1[(size_t)(co0 + r) * (CK * 3) + ci0 * 3 + kk];
    }
    __syncthreads();
    #pragma unroll 4
    for (int ci = 0; ci < 32; ++ci) {
      float kv[6];
      #pragma unroll
      for (int j = 0; j < 6; ++j) kv[j] = kLDS[ci][tx * 4 + j];
      #pragma unroll
      for (int i = 0; i < 4; ++i) {
        float wa = wLDS[ty * 4 + i][ci * 3 + 0];
        float wb = wLDS[ty * 4 + i][ci * 3 + 1];
        float wc = wLDS[ty * 4 + i][ci * 3 + 2];
        #pragma unroll
        for (int j = 0; j < 4; ++j)
          acc[i][j] += wa * kv[j] + wb * kv[j + 1] + wc * kv[j + 2];
      }
    }
    __syncthreads();
  }
  #pragma unroll
  for (int i = 0; i < 4; ++i) {
    const int co = co0 + ty * 4 + i;
    const float bias = b1[co];
    #pragma unroll
    for (int j = 0; j < 4; ++j) {
      int t = t0 + tx * 4 + j;
      if (t < TEN) {
        float v = acc[i][j] + bias;
        k1[((size_t)b * C1 + co) * TEN + t] = v > 0.f ? v : 0.f;
      }
    }
  }
}

// ---------------------------------------------------------------------------
// Key conv2 (verbatim R6)
// ---------------------------------------------------------------------------
__global__ __launch_bounds__(256) void kconv2_kernel(
    const float* __restrict__ k1, const float* __restrict__ w2,
    const float* __restrict__ b2, float* __restrict__ kfeat) {
  __shared__ float kLDS[128][64];
  const int b = blockIdx.x / 7;
  const int tt = blockIdx.x % 7;
  const int t0 = tt * 64;
  const int tid = threadIdx.x;
  float acc[20] = {};
  for (int c0 = 0; c0 < C1; c0 += 128) {
    for (int idx = tid; idx < 128 * 64; idx += 256) {
      int r = idx >> 6, j = idx & 63;
      int t = t0 + j;
      kLDS[r][j] = (t < TEN) ? k1[((size_t)b * C1 + c0 + r) * TEN + t] : 0.f;
    }
    __syncthreads();
    #pragma unroll
    for (int i = 0; i < 20; ++i) {
      int idx = tid + 256 * i;
      int a = idx >> 6, j = idx & 63;
      const float* wrow = &w2[(size_t)a * C1 + c0];
      float s = 0.f;
      #pragma unroll 8
      for (int ci = 0; ci < 128; ++ci)
        s += wrow[ci] * kLDS[ci][j];
      acc[i] += s;
    }
    __syncthreads();
  }
  #pragma unroll
  for (int i = 0; i < 20; ++i) {
    int idx = tid + 256 * i;
    int a = idx >> 6, j = idx & 63;
    int t = t0 + j;
    if (t < TEN) kfeat[((size_t)b * CA + a) * TEN + t] = acc[i] + b2[a];
  }
}

// ---------------------------------------------------------------------------
// Naive query path (verbatim R6)
// ---------------------------------------------------------------------------
__global__ __launch_bounds__(256) void qnaive1_kernel(
    const float* __restrict__ q, const float* __restrict__ w,
    const float* __restrict__ bias, float* __restrict__ q1) {
  const int t = blockIdx.x * 256 + threadIdx.x;
  const int c1 = blockIdx.y;
  const int b  = blockIdx.z;
  if (t >= TDE) return;
  float s = bias[c1];
  for (int c = 0; c < CQ; ++c) {
    const float* qr = &q[((size_t)b * CQ + c) * TDE];
    const float* wr = &w[((size_t)c1 * CQ + c) * 3];
    if (t >= 1)        s += wr[0] * qr[t - 1];
    s += wr[1] * qr[t];
    if (t + 1 < TDE)   s += wr[2] * qr[t + 1];
  }
  q1[((size_t)b * CQ2 + c1) * TDE + t] = s;
}

__global__ __launch_bounds__(256) void qnaive2_kernel(
    const float* __restrict__ q1, const float* __restrict__ w,
    const float* __restrict__ bias, float* __restrict__ q2) {
  const int t = blockIdx.x * 256 + threadIdx.x;
  const int a = blockIdx.y;
  const int b = blockIdx.z;
  if (t >= TDE) return;
  float s = bias[a];
  for (int c = 0; c < CQ2; ++c) {
    float v = q1[((size_t)b * CQ2 + c) * TDE + t];
    s += w[(size_t)a * CQ2 + c] * (v > 0.f ? v : 0.f);
  }
  q2[((size_t)b * CQ + a) * TDE + t] = s > 0.f ? s : 0.f;
}

__global__ __launch_bounds__(256) void qnaive3_kernel(
    const float* __restrict__ q2, const float* __restrict__ w,
    const float* __restrict__ bias, float* __restrict__ q3) {
  const int t = blockIdx.x * 256 + threadIdx.x;
  const int a = blockIdx.y;
  const int b = blockIdx.z;
  if (t >= TDE) return;
  float s = bias[a];
  for (int c = 0; c < CQ; ++c)
    s += w[(size_t)a * CQ + c] * q2[((size_t)b * CQ + c) * TDE + t];
  q3[((size_t)b * CA + a) * TDE + t] = s;
}

// ---------------------------------------------------------------------------
// Naive attention — FLOAT32 outputs. One block per (b,t) row.
// ---------------------------------------------------------------------------
__global__ __launch_bounds__(512) void attn_naive_kernel(
    const float* __restrict__ q3, const float* __restrict__ kfeat,
    const int* __restrict__ mask, float* __restrict__ out_attn,
    float* __restrict__ out_logp) {
  __shared__ float qrow[CA];
  __shared__ float lpv[512];
  __shared__ float red[512];
  const int b = blockIdx.y;
  const int t = blockIdx.x;
  const int s = threadIdx.x;
  if (s < CA) qrow[s] = q3[((size_t)b * CA + s) * TDE + t];
  __syncthreads();
  float lp = -INFINITY;
  if (s < TEN) {
    float d = 0.f;
    for (int a = 0; a < CA; ++a) {
      float dv = qrow[a] - kfeat[((size_t)b * CA + a) * TEN + s];
      d += dv * dv;
    }
    lp = mask[(size_t)b * TEN + s] ? (-TEMP) * d : -INFINITY;
    out_logp[((size_t)(b * TDE + t)) * TEN + s] = lp;
  }
  lpv[s] = lp;
  red[s] = lp;
  __syncthreads();
  for (int o = 256; o > 0; o >>= 1) {
    if (s < o) red[s] = fmaxf(red[s], red[s + o]);
    __syncthreads();
  }
  const float m = red[0];
  __syncthreads();
  float e = (s < TEN && lpv[s] != -INFINITY) ? __expf(lpv[s] - m) : 0.f;
  red[s] = e;
  __syncthreads();
  for (int o = 256; o > 0; o >>= 1) {
    if (s < o) red[s] += red[s + o];
    __syncthreads();
  }
  const float inv = 1.0f / red[0];
  if (s < TEN)
    out_attn[((size_t)(b * TDE + t)) * TEN + s] = e * inv;
}

__global__ __launch_bounds__(256) void sentinel_kernel(float* out, long long n,
                                                       float v) {
  long long i = (long long)blockIdx.x * 256 + threadIdx.x;
  long long stride = (long long)gridDim.x * 256;
  for (; i < n; i += stride) out[i] = v;
}

extern "C" void kernel_launch(void* const* d_in, const int* in_sizes, int n_in,
                              void* d_out, int out_size, void* d_ws, size_t ws_size,
                              hipStream_t stream) {
  const float* queries = (const float*)d_in[0];
  const float* keys    = (const float*)d_in[1];
  const int*   mask    = (const int*)d_in[2];
  const float* kw1 = (const float*)d_in[3];
  const float* kb1 = (const float*)d_in[4];
  const float* kw2 = (const float*)d_in[5];
  const float* kb2 = (const float*)d_in[6];
  const float* qw1 = (const float*)d_in[7];
  const float* qb1 = (const float*)d_in[8];
  const float* qw2 = (const float*)d_in[9];
  const float* qb2 = (const float*)d_in[10];
  const float* qw3 = (const float*)d_in[11];
  const float* qb3 = (const float*)d_in[12];
  float* out = (float*)d_out;

  const int expect[13] = {5120000, 6553600, 12800, 1572864, 1024, 81920, 80,
                          38400, 160, 12800, 80, 6400, 80};
  bool ok = (n_in == 13);
  for (int i = 0; ok && i < 13; ++i) ok = (in_sizes[i] == expect[i]);
  if (!ok) {
    sentinel_kernel<<<dim3(2048), dim3(256), 0, stream>>>(out, out_size, 100.f);
    return;
  }
  if (ws_size < 86016000) {
    sentinel_kernel<<<dim3(2048), dim3(256), 0, stream>>>(out, out_size, 200.f);
    return;
  }

  char* ws = (char*)d_ws;
  // ws layout (bytes), overlay stream-ordered (k1 reuses dead q1/q2 space):
  //   q1    f32 [32][160][2000] : [0,          40,960,000)
  //   q2    f32 [32][80][2000]  : [40,960,000, 61,440,000)
  //   q3    f32 [32][80][2000]  : [61,440,000, 81,920,000)
  //   k1    f32 [32][1024][400] : [0,          52,428,800)  (after q1/q2 dead)
  //   kfeat f32 [32][80][400]   : [81,920,000, 86,016,000)
  float* q1    = (float*)ws;
  float* q2    = (float*)(ws + 40960000);
  float* q3    = (float*)(ws + 61440000);
  float* k1    = (float*)ws;
  float* kfeat = (float*)(ws + 81920000);

  // Output: float32. attn at [0, 25.6M) elements, logp at [25.6M, 51.2M).
  const long long HALF = 25600000LL;
  float* out_attn = out;
  float* out_logp = out + HALF;

  qnaive1_kernel<<<dim3(8, CQ2, NB), dim3(256), 0, stream>>>(queries, qw1, qb1, q1);
  qnaive2_kernel<<<dim3(8, CQ, NB), dim3(256), 0, stream>>>(q1, qw2, qb2, q2);
  qnaive3_kernel<<<dim3(8, CA, NB), dim3(256), 0, stream>>>(q2, qw3, qb3, q3);
  kconv1_kernel<<<dim3(16, NB * 7), dim3(256), 0, stream>>>(keys, kw1, kb1, k1);
  kconv2_kernel<<<dim3(NB * 7), dim3(256), 0, stream>>>(k1, kw2, kb2, kfeat);
  attn_naive_kernel<<<dim3(TDE, NB), dim3(512), 0, stream>>>(q3, kfeat, mask,
                                                             out_attn, out_logp);
}

// Round 11
// 2276.747 us; speedup vs baseline: 1.3171x; 1.3171x over previous
//
#include <hip/hip_runtime.h>
#include <hip/hip_bf16.h>
#include <math.h>

#define NB 32
#define CK 512
#define C1 1024
#define CA 80
#define CQ 80
#define CQ2 160
#define TEN 400
#define TDE 2000

static constexpr float TEMP = 0.0005f;

// OUTPUT DTYPE: float32 (proven R9/R10). attn at float idx [0,25.6M),
// logp at [25.6M,51.2M).

// ---------------------------------------------------------------------------
// Key conv1 (verbatim R10): keys (*) kw1 pad=1 -> +bias -> relu -> k1 f32
// ---------------------------------------------------------------------------
__global__ __launch_bounds__(256) void kconv1_kernel(
    const float* __restrict__ keys, const float* __restrict__ w1,
    const float* __restrict__ b1, float* __restrict__ k1) {
  __shared__ float kLDS[32][66];
  __shared__ float wLDS[64][98];
  const int mtile = blockIdx.x;
  const int b  = blockIdx.y / 7;
  const int tt = blockIdx.y % 7;
  const int t0 = tt * 64;
  const int co0 = mtile * 64;
  const int tid = threadIdx.x;
  const int ty = tid >> 4, tx = tid & 15;
  float acc[4][4] = {};
  for (int ci0 = 0; ci0 < CK; ci0 += 32) {
    for (int idx = tid; idx < 32 * 66; idx += 256) {
      int r = idx / 66, j = idx % 66;
      int t = t0 - 1 + j;
      kLDS[r][j] = (t >= 0 && t < TEN) ? keys[((size_t)b * CK + ci0 + r) * TEN + t] : 0.f;
    }
    for (int idx = tid; idx < 64 * 96; idx += 256) {
      int r = idx / 96, kk = idx % 96;
      wLDS[r][kk] = w1[(size_t)(co0 + r) * (CK * 3) + ci0 * 3 + kk];
    }
    __syncthreads();
    #pragma unroll 4
    for (int ci = 0; ci < 32; ++ci) {
      float kv[6];
      #pragma unroll
      for (int j = 0; j < 6; ++j) kv[j] = kLDS[ci][tx * 4 + j];
      #pragma unroll
      for (int i = 0; i < 4; ++i) {
        float wa = wLDS[ty * 4 + i][ci * 3 + 0];
        float wb = wLDS[ty * 4 + i][ci * 3 + 1];
        float wc = wLDS[ty * 4 + i][ci * 3 + 2];
        #pragma unroll
        for (int j = 0; j < 4; ++j)
          acc[i][j] += wa * kv[j] + wb * kv[j + 1] + wc * kv[j + 2];
      }
    }
    __syncthreads();
  }
  #pragma unroll
  for (int i = 0; i < 4; ++i) {
    const int co = co0 + ty * 4 + i;
    const float bias = b1[co];
    #pragma unroll
    for (int j = 0; j < 4; ++j) {
      int t = t0 + tx * 4 + j;
      if (t < TEN) {
        float v = acc[i][j] + bias;
        k1[((size_t)b * C1 + co) * TEN + t] = v > 0.f ? v : 0.f;
      }
    }
  }
}

// ---------------------------------------------------------------------------
// Key conv2 (verbatim R10)
// ---------------------------------------------------------------------------
__global__ __launch_bounds__(256) void kconv2_kernel(
    const float* __restrict__ k1, const float* __restrict__ w2,
    const float* __restrict__ b2, float* __restrict__ kfeat) {
  __shared__ float kLDS[128][64];
  const int b = blockIdx.x / 7;
  const int tt = blockIdx.x % 7;
  const int t0 = tt * 64;
  const int tid = threadIdx.x;
  float acc[20] = {};
  for (int c0 = 0; c0 < C1; c0 += 128) {
    for (int idx = tid; idx < 128 * 64; idx += 256) {
      int r = idx >> 6, j = idx & 63;
      int t = t0 + j;
      kLDS[r][j] = (t < TEN) ? k1[((size_t)b * C1 + c0 + r) * TEN + t] : 0.f;
    }
    __syncthreads();
    #pragma unroll
    for (int i = 0; i < 20; ++i) {
      int idx = tid + 256 * i;
      int a = idx >> 6, j = idx & 63;
      const float* wrow = &w2[(size_t)a * C1 + c0];
      float s = 0.f;
      #pragma unroll 8
      for (int ci = 0; ci < 128; ++ci)
        s += wrow[ci] * kLDS[ci][j];
      acc[i] += s;
    }
    __syncthreads();
  }
  #pragma unroll
  for (int i = 0; i < 20; ++i) {
    int idx = tid + 256 * i;
    int a = idx >> 6, j = idx & 63;
    int t = t0 + j;
    if (t < TEN) kfeat[((size_t)b * CA + a) * TEN + t] = acc[i] + b2[a];
  }
}

// ---------------------------------------------------------------------------
// Fused query path (R2 structure, numerically validated by R4's probe):
// conv3(80->160,p1) -> relu -> conv1(160->80) -> relu -> conv1(80->80) -> q3
// ---------------------------------------------------------------------------
__global__ __launch_bounds__(256) void qpath_kernel(
    const float* __restrict__ queries,
    const float* __restrict__ w1, const float* __restrict__ b1,
    const float* __restrict__ w2, const float* __restrict__ b2,
    const float* __restrict__ w3, const float* __restrict__ b3,
    float* __restrict__ q3out) {
  __shared__ float s1[80 * 52];    // queries tile (halo), later q2
  __shared__ float s2[160 * 50];   // q1, later q3
  const int b = blockIdx.y;
  const int t0 = blockIdx.x * 50;
  const int tid = threadIdx.x;
  for (int idx = tid; idx < 80 * 52; idx += 256) {
    int c = idx / 52, j = idx % 52;
    int t = t0 - 1 + j;
    s1[idx] = (t >= 0 && t < TDE) ? queries[((size_t)b * CQ + c) * TDE + t] : 0.f;
  }
  __syncthreads();
  for (int idx = tid; idx < 160 * 50; idx += 256) {
    int c1 = idx / 50, t = idx % 50;
    const float* wr = &w1[(size_t)c1 * (CQ * 3)];
    const float* qc = &s1[t];
    float s = b1[c1];
    #pragma unroll 4
    for (int c = 0; c < 80; ++c)
      s += wr[c * 3 + 0] * qc[c * 52 + 0] + wr[c * 3 + 1] * qc[c * 52 + 1] +
           wr[c * 3 + 2] * qc[c * 52 + 2];
    s2[idx] = s;
  }
  __syncthreads();
  for (int idx = tid; idx < 80 * 50; idx += 256) {
    int a = idx / 50, t = idx % 50;
    const float* wr = &w2[(size_t)a * CQ2];
    float s = b2[a];
    #pragma unroll 8
    for (int c = 0; c < 160; ++c) {
      float v = s2[c * 50 + t];
      s += wr[c] * (v > 0.f ? v : 0.f);
    }
    s1[idx] = s > 0.f ? s : 0.f;
  }
  __syncthreads();
  for (int idx = tid; idx < 80 * 50; idx += 256) {
    int a = idx / 50, t = idx % 50;
    const float* wr = &w3[(size_t)a * CQ];
    float s = b3[a];
    #pragma unroll 8
    for (int c = 0; c < 80; ++c) s += wr[c] * s1[c * 50 + t];
    q3out[((size_t)b * CA + a) * TDE + t0 + t] = s;
  }
}

// ---------------------------------------------------------------------------
// Tiled attention (R2 QK structure + R5 shfl-free softmax), FLOAT32 outputs.
// Block = (b, 16 decoder rows). dist computed directly: sum_c (q-k)^2.
// ---------------------------------------------------------------------------
__global__ __launch_bounds__(256) void attn_kernel(
    const float* __restrict__ q3, const float* __restrict__ kfeat,
    const int* __restrict__ mask, float* __restrict__ out_attn,
    float* __restrict__ out_logp) {
  __shared__ float qT[80][16];
  __shared__ float lp[16][400];
  __shared__ float kLDS[80][64];
  __shared__ int mLDS[400];
  __shared__ float part[16][17];
  __shared__ float rowmax[16], rowinv[16];
  const int b = blockIdx.y;
  const int t0 = blockIdx.x * 16;
  const int tid = threadIdx.x;
  const int lane = tid & 63, w = tid >> 6;
  for (int idx = tid; idx < 80 * 16; idx += 256) {
    int c = idx >> 4, r = idx & 15;
    qT[c][r] = q3[((size_t)b * CA + c) * TDE + t0 + r];
  }
  for (int idx = tid; idx < 400; idx += 256) mLDS[idx] = mask[(size_t)b * TEN + idx];
  __syncthreads();
  for (int s0 = 0; s0 < TEN; s0 += 64) {
    for (int idx = tid; idx < 80 * 64; idx += 256) {
      int c = idx >> 6, j = idx & 63;
      int s = s0 + j;
      kLDS[c][j] = (s < TEN) ? kfeat[((size_t)b * CA + c) * TEN + s] : 0.f;
    }
    __syncthreads();
    float acc[4] = {0.f, 0.f, 0.f, 0.f};
    #pragma unroll 4
    for (int c = 0; c < 80; ++c) {
      float kv = kLDS[c][lane];
      #pragma unroll
      for (int i = 0; i < 4; ++i) {
        float d = qT[c][w * 4 + i] - kv;
        acc[i] += d * d;
      }
    }
    int s = s0 + lane;
    if (s < TEN) {
      #pragma unroll
      for (int i = 0; i < 4; ++i) lp[w * 4 + i][s] = acc[i];
    }
    __syncthreads();
  }
  // finalize logp (f32 store), keep lp in LDS
  for (int idx = tid; idx < 16 * 400; idx += 256) {
    int r = idx / 400, s = idx % 400;
    float v = mLDS[s] ? (-TEMP) * lp[r][s] : -INFINITY;
    lp[r][s] = v;
    out_logp[((size_t)(b * TDE + t0 + r)) * TEN + s] = v;
  }
  __syncthreads();
  // softmax: 16 sub-reducers per row (R5 scheme, shfl-free)
  const int g = tid >> 4;
  const int u = tid & 15;
  float pm = -INFINITY;
  for (int s = u; s < TEN; s += 16) pm = fmaxf(pm, lp[g][s]);
  part[g][u] = pm;
  __syncthreads();
  if (tid < 16) {
    float m = part[tid][0];
    #pragma unroll
    for (int k = 1; k < 16; ++k) m = fmaxf(m, part[tid][k]);
    rowmax[tid] = m;
  }
  __syncthreads();
  const float mg = rowmax[g];
  float ps = 0.f;
  for (int s = u; s < TEN; s += 16) {
    float v = lp[g][s];
    ps += (v != -INFINITY) ? __expf(v - mg) : 0.f;
  }
  part[g][u] = ps;
  __syncthreads();
  if (tid < 16) {
    float tot = 0.f;
    #pragma unroll
    for (int k = 0; k < 16; ++k) tot += part[tid][k];
    rowinv[tid] = 1.0f / tot;
  }
  __syncthreads();
  for (int idx = tid; idx < 16 * TEN; idx += 256) {
    int r = idx / TEN, s = idx % TEN;
    float v = lp[r][s];
    float e = (v != -INFINITY) ? __expf(v - rowmax[r]) * rowinv[r] : 0.f;
    out_attn[((size_t)(b * TDE + t0 + r)) * TEN + s] = e;
  }
}

extern "C" void kernel_launch(void* const* d_in, const int* in_sizes, int n_in,
                              void* d_out, int out_size, void* d_ws, size_t ws_size,
                              hipStream_t stream) {
  const float* queries = (const float*)d_in[0];
  const float* keys    = (const float*)d_in[1];
  const int*   mask    = (const int*)d_in[2];
  const float* kw1 = (const float*)d_in[3];
  const float* kb1 = (const float*)d_in[4];
  const float* kw2 = (const float*)d_in[5];
  const float* kb2 = (const float*)d_in[6];
  const float* qw1 = (const float*)d_in[7];
  const float* qb1 = (const float*)d_in[8];
  const float* qw2 = (const float*)d_in[9];
  const float* qb2 = (const float*)d_in[10];
  const float* qw3 = (const float*)d_in[11];
  const float* qb3 = (const float*)d_in[12];
  float* out = (float*)d_out;

  char* ws = (char*)d_ws;
  // ws layout (bytes):
  //   k1    f32 [32][1024][400] : [0,          52,428,800)
  //   q3    f32 [32][80][2000]  : [61,440,000, 81,920,000)
  //   kfeat f32 [32][80][400]   : [81,920,000, 86,016,000)
  float* k1    = (float*)ws;
  float* q3    = (float*)(ws + 61440000);
  float* kfeat = (float*)(ws + 81920000);

  const long long HALF = 25600000LL;
  float* out_attn = out;
  float* out_logp = out + HALF;

  qpath_kernel<<<dim3(40, NB), dim3(256), 0, stream>>>(queries, qw1, qb1, qw2, qb2,
                                                       qw3, qb3, q3);
  kconv1_kernel<<<dim3(16, NB * 7), dim3(256), 0, stream>>>(keys, kw1, kb1, k1);
  kconv2_kernel<<<dim3(NB * 7), dim3(256), 0, stream>>>(k1, kw2, kb2, kfeat);
  attn_kernel<<<dim3(125, NB), dim3(256), 0, stream>>>(q3, kfeat, mask,
                                                       out_attn, out_logp);
}

// Round 12
// 1436.382 us; speedup vs baseline: 2.0876x; 1.5851x over previous
//
#include <hip/hip_runtime.h>
#include <hip/hip_bf16.h>
#include <math.h>

#define NB 32
#define CK 512
#define C1 1024
#define CA 80
#define CQ 80
#define CQ2 160
#define TEN 400
#define TDE 2000
#define KDIM 1536
#define TPAD 448

static constexpr float TEMP = 0.0005f;

typedef __attribute__((ext_vector_type(8))) short short8;
typedef __attribute__((ext_vector_type(4))) float f32x4;

__device__ inline short f2bf(float v) {
  __hip_bfloat16 h = __float2bfloat16(v);
  return *(short*)&h;
}
__device__ inline float bf2f(short s) {
  __hip_bfloat16 h = *(__hip_bfloat16*)&s;
  return __bfloat162float(h);
}

// ---------------------------------------------------------------------------
// Prepass 1: w1 f32[1024][1536] -> bf16 (layout unchanged: [co][ci*3+dk])
// ---------------------------------------------------------------------------
__global__ __launch_bounds__(256) void cvt_w1_kernel(
    const float* __restrict__ w1, short* __restrict__ w1bf) {
  int i = blockIdx.x * 256 + threadIdx.x;   // grid covers 1,572,864
  if (i < C1 * KDIM) w1bf[i] = f2bf(w1[i]);
}

// ---------------------------------------------------------------------------
// Prepass 2: im2col, t-major: BmatT[b][t][k] = keys[b][k/3][t + k%3 - 1]
// t padded to 448 (pad rows left as garbage; their GEMM outputs are dropped).
// ---------------------------------------------------------------------------
__global__ __launch_bounds__(256) void im2col_kernel(
    const float* __restrict__ keys, short* __restrict__ BmatT) {
  const int t = blockIdx.x;          // 0..399
  const int b = blockIdx.y;
  const int tid = threadIdx.x;
  short* dst = BmatT + ((size_t)b * TPAD + t) * KDIM;
  #pragma unroll
  for (int i = 0; i < 6; ++i) {      // 6*256 = 1536
    int k = tid + i * 256;
    int ci = k / 3;
    int dk = k - ci * 3;
    int ts = t + dk - 1;
    float v = (ts >= 0 && ts < TEN) ? keys[((size_t)b * CK + ci) * TEN + ts] : 0.f;
    dst[k] = f2bf(v);
  }
}

// ---------------------------------------------------------------------------
// Key conv1 via MFMA: C[co][t] = sum_k w1bf[co][k] * BmatT[b][t][k]
// 64co x 64t tile, BK=32, 4 waves, 16x16x32 bf16 MFMA, XOR-swizzled LDS.
// Epilogue: +bias, relu, store bf16 k1.
// ---------------------------------------------------------------------------
__global__ __launch_bounds__(256) void kconv1_mfma_kernel(
    const short* __restrict__ w1bf, const short* __restrict__ BmatT,
    const float* __restrict__ b1, short* __restrict__ k1bf) {
  __shared__ short A_lds[2048];      // 64 rows x 32 k (bf16), swizzled
  __shared__ short B_lds[2048];
  const int co0 = blockIdx.x * 64;
  const int t0  = blockIdx.y * 64;
  const int b   = blockIdx.z;
  const int tid = threadIdx.x;
  const int l = tid & 63, w = tid >> 6;
  const int srow = tid >> 2, sslot = tid & 3;   // stage: row 0..63, 16B slot 0..3

  const char* gA = (const char*)(w1bf + (size_t)(co0 + srow) * KDIM + sslot * 8);
  const char* gB = (const char*)(BmatT + ((size_t)b * TPAD + t0 + srow) * KDIM + sslot * 8);
  const int wbyte = (srow * 64 + sslot * 16) ^ ((srow & 7) << 4);

  const int kslot = l >> 4;          // 0..3
  const int arow = w * 16 + (l & 15);
  const int abyte = (arow * 64 + kslot * 16) ^ ((arow & 7) << 4);
  int bbyte[4];
  #pragma unroll
  for (int g = 0; g < 4; ++g) {
    int brow = g * 16 + (l & 15);
    bbyte[g] = (brow * 64 + kslot * 16) ^ ((brow & 7) << 4);
  }

  f32x4 acc[4];
  #pragma unroll
  for (int g = 0; g < 4; ++g) acc[g] = (f32x4){0.f, 0.f, 0.f, 0.f};

  for (int kt = 0; kt < KDIM / 32; ++kt) {     // 48 iterations
    uint4 av = *(const uint4*)(gA + (size_t)kt * 64);
    uint4 bv = *(const uint4*)(gB + (size_t)kt * 64);
    __syncthreads();                 // previous iteration's reads complete
    *(uint4*)((char*)A_lds + wbyte) = av;
    *(uint4*)((char*)B_lds + wbyte) = bv;
    __syncthreads();
    short8 a = *(const short8*)((const char*)A_lds + abyte);
    #pragma unroll
    for (int g = 0; g < 4; ++g) {
      short8 bb = *(const short8*)((const char*)B_lds + bbyte[g]);
      acc[g] = __builtin_amdgcn_mfma_f32_16x16x32_bf16(a, bb, acc[g], 0, 0, 0);
    }
  }

  // Epilogue: C/D layout (m89-verified): row = (l>>4)*4 + r, col = l&15.
  #pragma unroll
  for (int g = 0; g < 4; ++g) {
    int t = t0 + g * 16 + (l & 15);
    if (t < TEN) {
      #pragma unroll
      for (int r = 0; r < 4; ++r) {
        int co = co0 + w * 16 + kslot * 4 + r;
        float v = acc[g][r] + b1[co];
        k1bf[((size_t)b * C1 + co) * TEN + t] = f2bf(v > 0.f ? v : 0.f);
      }
    }
  }
}

// ---------------------------------------------------------------------------
// Key conv2 (R11 structure; input now bf16, converted at LDS stage)
// ---------------------------------------------------------------------------
__global__ __launch_bounds__(256) void kconv2_kernel(
    const short* __restrict__ k1bf, const float* __restrict__ w2,
    const float* __restrict__ b2, float* __restrict__ kfeat) {
  __shared__ float kLDS[128][64];
  const int b = blockIdx.x / 7;
  const int tt = blockIdx.x % 7;
  const int t0 = tt * 64;
  const int tid = threadIdx.x;
  float acc[20] = {};
  for (int c0 = 0; c0 < C1; c0 += 128) {
    for (int idx = tid; idx < 128 * 64; idx += 256) {
      int r = idx >> 6, j = idx & 63;
      int t = t0 + j;
      kLDS[r][j] = (t < TEN) ? bf2f(k1bf[((size_t)b * C1 + c0 + r) * TEN + t]) : 0.f;
    }
    __syncthreads();
    #pragma unroll
    for (int i = 0; i < 20; ++i) {
      int idx = tid + 256 * i;
      int a = idx >> 6, j = idx & 63;
      const float* wrow = &w2[(size_t)a * C1 + c0];
      float s = 0.f;
      #pragma unroll 8
      for (int ci = 0; ci < 128; ++ci)
        s += wrow[ci] * kLDS[ci][j];
      acc[i] += s;
    }
    __syncthreads();
  }
  #pragma unroll
  for (int i = 0; i < 20; ++i) {
    int idx = tid + 256 * i;
    int a = idx >> 6, j = idx & 63;
    int t = t0 + j;
    if (t < TEN) kfeat[((size_t)b * CA + a) * TEN + t] = acc[i] + b2[a];
  }
}

// ---------------------------------------------------------------------------
// Fused query path (verbatim R11)
// ---------------------------------------------------------------------------
__global__ __launch_bounds__(256) void qpath_kernel(
    const float* __restrict__ queries,
    const float* __restrict__ w1, const float* __restrict__ b1,
    const float* __restrict__ w2, const float* __restrict__ b2,
    const float* __restrict__ w3, const float* __restrict__ b3,
    float* __restrict__ q3out) {
  __shared__ float s1[80 * 52];
  __shared__ float s2[160 * 50];
  const int b = blockIdx.y;
  const int t0 = blockIdx.x * 50;
  const int tid = threadIdx.x;
  for (int idx = tid; idx < 80 * 52; idx += 256) {
    int c = idx / 52, j = idx % 52;
    int t = t0 - 1 + j;
    s1[idx] = (t >= 0 && t < TDE) ? queries[((size_t)b * CQ + c) * TDE + t] : 0.f;
  }
  __syncthreads();
  for (int idx = tid; idx < 160 * 50; idx += 256) {
    int c1 = idx / 50, t = idx % 50;
    const float* wr = &w1[(size_t)c1 * (CQ * 3)];
    const float* qc = &s1[t];
    float s = b1[c1];
    #pragma unroll 4
    for (int c = 0; c < 80; ++c)
      s += wr[c * 3 + 0] * qc[c * 52 + 0] + wr[c * 3 + 1] * qc[c * 52 + 1] +
           wr[c * 3 + 2] * qc[c * 52 + 2];
    s2[idx] = s;
  }
  __syncthreads();
  for (int idx = tid; idx < 80 * 50; idx += 256) {
    int a = idx / 50, t = idx % 50;
    const float* wr = &w2[(size_t)a * CQ2];
    float s = b2[a];
    #pragma unroll 8
    for (int c = 0; c < 160; ++c) {
      float v = s2[c * 50 + t];
      s += wr[c] * (v > 0.f ? v : 0.f);
    }
    s1[idx] = s > 0.f ? s : 0.f;
  }
  __syncthreads();
  for (int idx = tid; idx < 80 * 50; idx += 256) {
    int a = idx / 50, t = idx % 50;
    const float* wr = &w3[(size_t)a * CQ];
    float s = b3[a];
    #pragma unroll 8
    for (int c = 0; c < 80; ++c) s += wr[c] * s1[c * 50 + t];
    q3out[((size_t)b * CA + a) * TDE + t0 + t] = s;
  }
}

// ---------------------------------------------------------------------------
// Tiled attention (verbatim R11), f32 outputs
// ---------------------------------------------------------------------------
__global__ __launch_bounds__(256) void attn_kernel(
    const float* __restrict__ q3, const float* __restrict__ kfeat,
    const int* __restrict__ mask, float* __restrict__ out_attn,
    float* __restrict__ out_logp) {
  __shared__ float qT[80][16];
  __shared__ float lp[16][400];
  __shared__ float kLDS[80][64];
  __shared__ int mLDS[400];
  __shared__ float part[16][17];
  __shared__ float rowmax[16], rowinv[16];
  const int b = blockIdx.y;
  const int t0 = blockIdx.x * 16;
  const int tid = threadIdx.x;
  const int lane = tid & 63, w = tid >> 6;
  for (int idx = tid; idx < 80 * 16; idx += 256) {
    int c = idx >> 4, r = idx & 15;
    qT[c][r] = q3[((size_t)b * CA + c) * TDE + t0 + r];
  }
  for (int idx = tid; idx < 400; idx += 256) mLDS[idx] = mask[(size_t)b * TEN + idx];
  __syncthreads();
  for (int s0 = 0; s0 < TEN; s0 += 64) {
    for (int idx = tid; idx < 80 * 64; idx += 256) {
      int c = idx >> 6, j = idx & 63;
      int s = s0 + j;
      kLDS[c][j] = (s < TEN) ? kfeat[((size_t)b * CA + c) * TEN + s] : 0.f;
    }
    __syncthreads();
    float acc[4] = {0.f, 0.f, 0.f, 0.f};
    #pragma unroll 4
    for (int c = 0; c < 80; ++c) {
      float kv = kLDS[c][lane];
      #pragma unroll
      for (int i = 0; i < 4; ++i) {
        float d = qT[c][w * 4 + i] - kv;
        acc[i] += d * d;
      }
    }
    int s = s0 + lane;
    if (s < TEN) {
      #pragma unroll
      for (int i = 0; i < 4; ++i) lp[w * 4 + i][s] = acc[i];
    }
    __syncthreads();
  }
  for (int idx = tid; idx < 16 * 400; idx += 256) {
    int r = idx / 400, s = idx % 400;
    float v = mLDS[s] ? (-TEMP) * lp[r][s] : -INFINITY;
    lp[r][s] = v;
    out_logp[((size_t)(b * TDE + t0 + r)) * TEN + s] = v;
  }
  __syncthreads();
  const int g = tid >> 4;
  const int u = tid & 15;
  float pm = -INFINITY;
  for (int s = u; s < TEN; s += 16) pm = fmaxf(pm, lp[g][s]);
  part[g][u] = pm;
  __syncthreads();
  if (tid < 16) {
    float m = part[tid][0];
    #pragma unroll
    for (int k = 1; k < 16; ++k) m = fmaxf(m, part[tid][k]);
    rowmax[tid] = m;
  }
  __syncthreads();
  const float mg = rowmax[g];
  float ps = 0.f;
  for (int s = u; s < TEN; s += 16) {
    float v = lp[g][s];
    ps += (v != -INFINITY) ? __expf(v - mg) : 0.f;
  }
  part[g][u] = ps;
  __syncthreads();
  if (tid < 16) {
    float tot = 0.f;
    #pragma unroll
    for (int k = 0; k < 16; ++k) tot += part[tid][k];
    rowinv[tid] = 1.0f / tot;
  }
  __syncthreads();
  for (int idx = tid; idx < 16 * TEN; idx += 256) {
    int r = idx / TEN, s = idx % TEN;
    float v = lp[r][s];
    float e = (v != -INFINITY) ? __expf(v - rowmax[r]) * rowinv[r] : 0.f;
    out_attn[((size_t)(b * TDE + t0 + r)) * TEN + s] = e;
  }
}

extern "C" void kernel_launch(void* const* d_in, const int* in_sizes, int n_in,
                              void* d_out, int out_size, void* d_ws, size_t ws_size,
                              hipStream_t stream) {
  const float* queries = (const float*)d_in[0];
  const float* keys    = (const float*)d_in[1];
  const int*   mask    = (const int*)d_in[2];
  const float* kw1 = (const float*)d_in[3];
  const float* kb1 = (const float*)d_in[4];
  const float* kw2 = (const float*)d_in[5];
  const float* kb2 = (const float*)d_in[6];
  const float* qw1 = (const float*)d_in[7];
  const float* qb1 = (const float*)d_in[8];
  const float* qw2 = (const float*)d_in[9];
  const float* qb2 = (const float*)d_in[10];
  const float* qw3 = (const float*)d_in[11];
  const float* qb3 = (const float*)d_in[12];
  float* out = (float*)d_out;

  char* ws = (char*)d_ws;
  // ws layout (bytes), stream-ordered overlays:
  //   BmatT bf16 [32][448][1536] : [0,          44,040,192)  dead after kconv1
  //   w1bf  bf16 [1024][1536]    : [44,040,192, 47,185,920)  dead after kconv1
  //   k1bf  bf16 [32][1024][400] : [47,185,920, 73,400,320)  dead after kconv2
  //   q3    f32  [32][80][2000]  : [0,          20,480,000)  overlays BmatT
  //   kfeat f32  [32][80][400]   : [20,480,000, 24,576,000)  overlays BmatT
  short* BmatT = (short*)ws;
  short* w1bf  = (short*)(ws + 44040192);
  short* k1bf  = (short*)(ws + 47185920);
  float* q3    = (float*)ws;
  float* kfeat = (float*)(ws + 20480000);

  const long long HALF = 25600000LL;
  float* out_attn = out;
  float* out_logp = out + HALF;

  cvt_w1_kernel<<<dim3((C1 * KDIM + 255) / 256), dim3(256), 0, stream>>>(kw1, w1bf);
  im2col_kernel<<<dim3(TEN, NB), dim3(256), 0, stream>>>(keys, BmatT);
  kconv1_mfma_kernel<<<dim3(16, 7, NB), dim3(256), 0, stream>>>(w1bf, BmatT, kb1, k1bf);
  kconv2_kernel<<<dim3(NB * 7), dim3(256), 0, stream>>>(k1bf, kw2, kb2, kfeat);
  qpath_kernel<<<dim3(40, NB), dim3(256), 0, stream>>>(queries, qw1, qb1, qw2, qb2,
                                                       qw3, qb3, q3);
  attn_kernel<<<dim3(125, NB), dim3(256), 0, stream>>>(q3, kfeat, mask,
                                                       out_attn, out_logp);
}

// Round 13
// 1032.475 us; speedup vs baseline: 2.9043x; 1.3912x over previous
//
#include <hip/hip_runtime.h>
#include <hip/hip_bf16.h>
#include <math.h>

#define NB 32
#define CK 512
#define C1 1024
#define CA 80
#define CQ 80
#define CQ2 160
#define TEN 400
#define TDE 2000
#define KDIM 1536
#define TPAD 448
#define TQP 2048

static constexpr float TEMP = 0.0005f;

typedef __attribute__((ext_vector_type(8))) short short8;
typedef __attribute__((ext_vector_type(4))) float f32x4;

__device__ inline short f2bf(float v) {
  __hip_bfloat16 h = __float2bfloat16(v);
  return *(short*)&h;
}
__device__ inline float bf2f(short s) {
  __hip_bfloat16 h = *(__hip_bfloat16*)&s;
  return __bfloat162float(h);
}

// ---------------------------------------------------------------------------
// Prepass: w1 f32[1024][1536] -> bf16 (layout unchanged)
// ---------------------------------------------------------------------------
__global__ __launch_bounds__(256) void cvt_w1_kernel(
    const float* __restrict__ w1, short* __restrict__ w1bf) {
  int i = blockIdx.x * 256 + threadIdx.x;
  if (i < C1 * KDIM) w1bf[i] = f2bf(w1[i]);
}

// ---------------------------------------------------------------------------
// Prepass: generic pad-convert f32 [M][K] -> bf16 [Mp][Kp] (zero pad)
// ---------------------------------------------------------------------------
__global__ __launch_bounds__(256) void cvt_pad_kernel(
    const float* __restrict__ src, short* __restrict__ dst,
    int M, int K, int Mp, int Kp) {
  int i = blockIdx.x * 256 + threadIdx.x;
  if (i >= Mp * Kp) return;
  int r = i / Kp, c = i - r * Kp;
  float v = (r < M && c < K) ? src[(size_t)r * K + c] : 0.f;
  dst[i] = f2bf(v);
}

// ---------------------------------------------------------------------------
// Prepass: keys im2col, t-major: BmatT[b][t][k] = keys[b][k/3][t + k%3 - 1]
// ---------------------------------------------------------------------------
__global__ __launch_bounds__(256) void im2col_kernel(
    const float* __restrict__ keys, short* __restrict__ BmatT) {
  const int t = blockIdx.x;
  const int b = blockIdx.y;
  const int tid = threadIdx.x;
  short* dst = BmatT + ((size_t)b * TPAD + t) * KDIM;
  #pragma unroll
  for (int i = 0; i < 6; ++i) {
    int k = tid + i * 256;
    int ci = k / 3;
    int dk = k - ci * 3;
    int ts = t + dk - 1;
    float v = (ts >= 0 && ts < TEN) ? keys[((size_t)b * CK + ci) * TEN + ts] : 0.f;
    dst[k] = f2bf(v);
  }
}

// ---------------------------------------------------------------------------
// Prepass: queries im2col: Bq[b][t][k], k in [0,256): k<240 -> q[b][k/3][t+k%3-1]
// Rows t>=2000 zeroed.
// ---------------------------------------------------------------------------
__global__ __launch_bounds__(256) void im2col_q_kernel(
    const float* __restrict__ queries, short* __restrict__ Bq) {
  const int t = blockIdx.x;          // 0..2047
  const int b = blockIdx.y;
  const int k = threadIdx.x;         // 0..255
  float v = 0.f;
  if (t < TDE && k < 240) {
    int ci = k / 3, dk = k - ci * 3, ts = t + dk - 1;
    v = (ts >= 0 && ts < TDE) ? queries[((size_t)b * CQ + ci) * TDE + ts] : 0.f;
  }
  Bq[((size_t)b * TQP + t) * 256 + k] = f2bf(v);
}

// ---------------------------------------------------------------------------
// Key conv1 via MFMA (verbatim R12, proven)
// ---------------------------------------------------------------------------
__global__ __launch_bounds__(256) void kconv1_mfma_kernel(
    const short* __restrict__ w1bf, const short* __restrict__ BmatT,
    const float* __restrict__ b1, short* __restrict__ k1bf) {
  __shared__ short A_lds[2048];
  __shared__ short B_lds[2048];
  const int co0 = blockIdx.x * 64;
  const int t0  = blockIdx.y * 64;
  const int b   = blockIdx.z;
  const int tid = threadIdx.x;
  const int l = tid & 63, w = tid >> 6;
  const int srow = tid >> 2, sslot = tid & 3;

  const char* gA = (const char*)(w1bf + (size_t)(co0 + srow) * KDIM + sslot * 8);
  const char* gB = (const char*)(BmatT + ((size_t)b * TPAD + t0 + srow) * KDIM + sslot * 8);
  const int wbyte = (srow * 64 + sslot * 16) ^ ((srow & 7) << 4);

  const int kslot = l >> 4;
  const int arow = w * 16 + (l & 15);
  const int abyte = (arow * 64 + kslot * 16) ^ ((arow & 7) << 4);
  int bbyte[4];
  #pragma unroll
  for (int g = 0; g < 4; ++g) {
    int brow = g * 16 + (l & 15);
    bbyte[g] = (brow * 64 + kslot * 16) ^ ((brow & 7) << 4);
  }

  f32x4 acc[4];
  #pragma unroll
  for (int g = 0; g < 4; ++g) acc[g] = (f32x4){0.f, 0.f, 0.f, 0.f};

  for (int kt = 0; kt < KDIM / 32; ++kt) {
    uint4 av = *(const uint4*)(gA + (size_t)kt * 64);
    uint4 bv = *(const uint4*)(gB + (size_t)kt * 64);
    __syncthreads();
    *(uint4*)((char*)A_lds + wbyte) = av;
    *(uint4*)((char*)B_lds + wbyte) = bv;
    __syncthreads();
    short8 a = *(const short8*)((const char*)A_lds + abyte);
    #pragma unroll
    for (int g = 0; g < 4; ++g) {
      short8 bb = *(const short8*)((const char*)B_lds + bbyte[g]);
      acc[g] = __builtin_amdgcn_mfma_f32_16x16x32_bf16(a, bb, acc[g], 0, 0, 0);
    }
  }
  #pragma unroll
  for (int g = 0; g < 4; ++g) {
    int t = t0 + g * 16 + (l & 15);
    if (t < TEN) {
      #pragma unroll
      for (int r = 0; r < 4; ++r) {
        int co = co0 + w * 16 + kslot * 4 + r;
        float v = acc[g][r] + b1[co];
        k1bf[((size_t)b * C1 + co) * TEN + t] = f2bf(v > 0.f ? v : 0.f);
      }
    }
  }
}

// ---------------------------------------------------------------------------
// Generic small GEMM for q-path (same tile/swizzle/C-mapping as kconv1_mfma).
// MODE 1: bf16 out[b][t][co] (t-major chain operand; co in [M,outCols) -> 0)
// MODE 2: f32  out[b][co][t]
// ---------------------------------------------------------------------------
template <int MODE, bool RELU>
__global__ __launch_bounds__(256) void qgemm_kernel(
    const short* __restrict__ A, const short* __restrict__ B,
    const float* __restrict__ bias, void* __restrict__ outv,
    int M, int Kpad, int kiters, int Nvalid, int outCols,
    size_t bBatchStride, size_t outBatchStride, int outLD) {
  __shared__ short A_lds[2048];
  __shared__ short B_lds[2048];
  const int co0 = blockIdx.x * 64;
  const int t0  = blockIdx.y * 64;
  const int b   = blockIdx.z;
  const int tid = threadIdx.x;
  const int l = tid & 63, w = tid >> 6;
  const int srow = tid >> 2, sslot = tid & 3;

  const short* gA = A + (size_t)(co0 + srow) * Kpad + sslot * 8;
  const short* gB = B + (size_t)b * bBatchStride + (size_t)(t0 + srow) * Kpad + sslot * 8;
  const int wbyte = (srow * 64 + sslot * 16) ^ ((srow & 7) << 4);

  const int kslot = l >> 4;
  const int arow = w * 16 + (l & 15);
  const int abyte = (arow * 64 + kslot * 16) ^ ((arow & 7) << 4);
  int bbyte[4];
  #pragma unroll
  for (int g = 0; g < 4; ++g) {
    int brow = g * 16 + (l & 15);
    bbyte[g] = (brow * 64 + kslot * 16) ^ ((brow & 7) << 4);
  }

  f32x4 acc[4];
  #pragma unroll
  for (int g = 0; g < 4; ++g) acc[g] = (f32x4){0.f, 0.f, 0.f, 0.f};

  for (int kt = 0; kt < kiters; ++kt) {
    uint4 av = *(const uint4*)(gA + kt * 32);
    uint4 bv = *(const uint4*)(gB + kt * 32);
    __syncthreads();
    *(uint4*)((char*)A_lds + wbyte) = av;
    *(uint4*)((char*)B_lds + wbyte) = bv;
    __syncthreads();
    short8 a = *(const short8*)((const char*)A_lds + abyte);
    #pragma unroll
    for (int g = 0; g < 4; ++g) {
      short8 bb = *(const short8*)((const char*)B_lds + bbyte[g]);
      acc[g] = __builtin_amdgcn_mfma_f32_16x16x32_bf16(a, bb, acc[g], 0, 0, 0);
    }
  }

  #pragma unroll
  for (int g = 0; g < 4; ++g) {
    int t = t0 + g * 16 + (l & 15);
    if (t >= Nvalid) continue;
    #pragma unroll
    for (int r = 0; r < 4; ++r) {
      int co = co0 + w * 16 + kslot * 4 + r;
      if (MODE == 1) {
        if (co < outCols) {
          float v = 0.f;
          if (co < M) {
            v = acc[g][r] + bias[co];
            if (RELU) v = v > 0.f ? v : 0.f;
          }
          ((short*)outv)[(size_t)b * outBatchStride + (size_t)t * outLD + co] = f2bf(v);
        }
      } else {  // MODE 2
        if (co < M) {
          float v = acc[g][r] + bias[co];
          if (RELU) v = v > 0.f ? v : 0.f;
          ((float*)outv)[(size_t)b * outBatchStride + (size_t)co * outLD + t] = v;
        }
      }
    }
  }
}

// ---------------------------------------------------------------------------
// Key conv2 (verbatim R12)
// ---------------------------------------------------------------------------
__global__ __launch_bounds__(256) void kconv2_kernel(
    const short* __restrict__ k1bf, const float* __restrict__ w2,
    const float* __restrict__ b2, float* __restrict__ kfeat) {
  __shared__ float kLDS[128][64];
  const int b = blockIdx.x / 7;
  const int tt = blockIdx.x % 7;
  const int t0 = tt * 64;
  const int tid = threadIdx.x;
  float acc[20] = {};
  for (int c0 = 0; c0 < C1; c0 += 128) {
    for (int idx = tid; idx < 128 * 64; idx += 256) {
      int r = idx >> 6, j = idx & 63;
      int t = t0 + j;
      kLDS[r][j] = (t < TEN) ? bf2f(k1bf[((size_t)b * C1 + c0 + r) * TEN + t]) : 0.f;
    }
    __syncthreads();
    #pragma unroll
    for (int i = 0; i < 20; ++i) {
      int idx = tid + 256 * i;
      int a = idx >> 6, j = idx & 63;
      const float* wrow = &w2[(size_t)a * C1 + c0];
      float s = 0.f;
      #pragma unroll 8
      for (int ci = 0; ci < 128; ++ci)
        s += wrow[ci] * kLDS[ci][j];
      acc[i] += s;
    }
    __syncthreads();
  }
  #pragma unroll
  for (int i = 0; i < 20; ++i) {
    int idx = tid + 256 * i;
    int a = idx >> 6, j = idx & 63;
    int t = t0 + j;
    if (t < TEN) kfeat[((size_t)b * CA + a) * TEN + t] = acc[i] + b2[a];
  }
}

// ---------------------------------------------------------------------------
// Tiled attention (verbatim R12), f32 outputs
// ---------------------------------------------------------------------------
__global__ __launch_bounds__(256) void attn_kernel(
    const float* __restrict__ q3, const float* __restrict__ kfeat,
    const int* __restrict__ mask, float* __restrict__ out_attn,
    float* __restrict__ out_logp) {
  __shared__ float qT[80][16];
  __shared__ float lp[16][400];
  __shared__ float kLDS[80][64];
  __shared__ int mLDS[400];
  __shared__ float part[16][17];
  __shared__ float rowmax[16], rowinv[16];
  const int b = blockIdx.y;
  const int t0 = blockIdx.x * 16;
  const int tid = threadIdx.x;
  const int lane = tid & 63, w = tid >> 6;
  for (int idx = tid; idx < 80 * 16; idx += 256) {
    int c = idx >> 4, r = idx & 15;
    qT[c][r] = q3[((size_t)b * CA + c) * TDE + t0 + r];
  }
  for (int idx = tid; idx < 400; idx += 256) mLDS[idx] = mask[(size_t)b * TEN + idx];
  __syncthreads();
  for (int s0 = 0; s0 < TEN; s0 += 64) {
    for (int idx = tid; idx < 80 * 64; idx += 256) {
      int c = idx >> 6, j = idx & 63;
      int s = s0 + j;
      kLDS[c][j] = (s < TEN) ? kfeat[((size_t)b * CA + c) * TEN + s] : 0.f;
    }
    __syncthreads();
    float acc[4] = {0.f, 0.f, 0.f, 0.f};
    #pragma unroll 4
    for (int c = 0; c < 80; ++c) {
      float kv = kLDS[c][lane];
      #pragma unroll
      for (int i = 0; i < 4; ++i) {
        float d = qT[c][w * 4 + i] - kv;
        acc[i] += d * d;
      }
    }
    int s = s0 + lane;
    if (s < TEN) {
      #pragma unroll
      for (int i = 0; i < 4; ++i) lp[w * 4 + i][s] = acc[i];
    }
    __syncthreads();
  }
  for (int idx = tid; idx < 16 * 400; idx += 256) {
    int r = idx / 400, s = idx % 400;
    float v = mLDS[s] ? (-TEMP) * lp[r][s] : -INFINITY;
    lp[r][s] = v;
    out_logp[((size_t)(b * TDE + t0 + r)) * TEN + s] = v;
  }
  __syncthreads();
  const int g = tid >> 4;
  const int u = tid & 15;
  float pm = -INFINITY;
  for (int s = u; s < TEN; s += 16) pm = fmaxf(pm, lp[g][s]);
  part[g][u] = pm;
  __syncthreads();
  if (tid < 16) {
    float m = part[tid][0];
    #pragma unroll
    for (int k = 1; k < 16; ++k) m = fmaxf(m, part[tid][k]);
    rowmax[tid] = m;
  }
  __syncthreads();
  const float mg = rowmax[g];
  float ps = 0.f;
  for (int s = u; s < TEN; s += 16) {
    float v = lp[g][s];
    ps += (v != -INFINITY) ? __expf(v - mg) : 0.f;
  }
  part[g][u] = ps;
  __syncthreads();
  if (tid < 16) {
    float tot = 0.f;
    #pragma unroll
    for (int k = 0; k < 16; ++k) tot += part[tid][k];
    rowinv[tid] = 1.0f / tot;
  }
  __syncthreads();
  for (int idx = tid; idx < 16 * TEN; idx += 256) {
    int r = idx / TEN, s = idx % TEN;
    float v = lp[r][s];
    float e = (v != -INFINITY) ? __expf(v - rowmax[r]) * rowinv[r] : 0.f;
    out_attn[((size_t)(b * TDE + t0 + r)) * TEN + s] = e;
  }
}

extern "C" void kernel_launch(void* const* d_in, const int* in_sizes, int n_in,
                              void* d_out, int out_size, void* d_ws, size_t ws_size,
                              hipStream_t stream) {
  const float* queries = (const float*)d_in[0];
  const float* keys    = (const float*)d_in[1];
  const int*   mask    = (const int*)d_in[2];
  const float* kw1 = (const float*)d_in[3];
  const float* kb1 = (const float*)d_in[4];
  const float* kw2 = (const float*)d_in[5];
  const float* kb2 = (const float*)d_in[6];
  const float* qw1 = (const float*)d_in[7];
  const float* qb1 = (const float*)d_in[8];
  const float* qw2 = (const float*)d_in[9];
  const float* qb2 = (const float*)d_in[10];
  const float* qw3 = (const float*)d_in[11];
  const float* qb3 = (const float*)d_in[12];
  float* out = (float*)d_out;

  char* ws = (char*)d_ws;
  // ws overlays (stream-ordered; all within proven 86,016,000 B):
  //  phase K: BmatT [0,44.04M) | w1bf [44.04M,47.19M) | k1bf [47.19M,73.40M)
  //  phase Q (after kconv2): Bq [0,33.55M) | q1bf [33.55M,54.53M) |
  //           q2bf [54.53M,67.11M) | wq [67.11M,67.28M) (in dead k1bf)
  //  phase A: q3 f32 [0,20.48M) (Bq dead) | kfeat [81.92M,86.02M)
  short* BmatT = (short*)ws;
  short* w1bf  = (short*)(ws + 44040192);
  short* k1bf  = (short*)(ws + 47185920);
  short* Bq    = (short*)ws;
  short* q1bf  = (short*)(ws + 33554432);
  short* q2bf  = (short*)(ws + 54525952);
  short* w1q   = (short*)(ws + 67108864);
  short* w2q   = (short*)(ws + 67207168);
  short* w3q   = (short*)(ws + 67248128);
  float* q3    = (float*)ws;
  float* kfeat = (float*)(ws + 81920000);

  const long long HALF = 25600000LL;
  float* out_attn = out;
  float* out_logp = out + HALF;

  // --- key path ---
  cvt_w1_kernel<<<dim3((C1 * KDIM + 255) / 256), dim3(256), 0, stream>>>(kw1, w1bf);
  im2col_kernel<<<dim3(TEN, NB), dim3(256), 0, stream>>>(keys, BmatT);
  kconv1_mfma_kernel<<<dim3(16, 7, NB), dim3(256), 0, stream>>>(w1bf, BmatT, kb1, k1bf);
  kconv2_kernel<<<dim3(NB * 7), dim3(256), 0, stream>>>(k1bf, kw2, kb2, kfeat);

  // --- query path (MFMA chain) ---
  cvt_pad_kernel<<<dim3((192 * 256 + 255) / 256), dim3(256), 0, stream>>>(
      qw1, w1q, CQ2, 240, 192, 256);
  cvt_pad_kernel<<<dim3((128 * 160 + 255) / 256), dim3(256), 0, stream>>>(
      qw2, w2q, CA, CQ2, 128, 160);
  cvt_pad_kernel<<<dim3((128 * 96 + 255) / 256), dim3(256), 0, stream>>>(
      qw3, w3q, CA, CQ, 128, 96);
  im2col_q_kernel<<<dim3(TQP, NB), dim3(256), 0, stream>>>(queries, Bq);
  qgemm_kernel<1, true><<<dim3(3, TQP / 64, NB), dim3(256), 0, stream>>>(
      w1q, Bq, qb1, q1bf, CQ2, 256, 8, TDE, 160,
      (size_t)TQP * 256, (size_t)TQP * 160, 160);
  qgemm_kernel<1, true><<<dim3(2, TQP / 64, NB), dim3(256), 0, stream>>>(
      w2q, q1bf, qb2, q2bf, CA, 160, 5, TDE, 96,
      (size_t)TQP * 160, (size_t)TQP * 96, 96);
  qgemm_kernel<2, false><<<dim3(2, TQP / 64, NB), dim3(256), 0, stream>>>(
      w3q, q2bf, qb3, q3, CA, 96, 3, TDE, 80,
      (size_t)TQP * 96, (size_t)CA * TDE, TDE);

  // --- attention ---
  attn_kernel<<<dim3(125, NB), dim3(256), 0, stream>>>(q3, kfeat, mask,
                                                       out_attn, out_logp);
}

// Round 14
// 616.937 us; speedup vs baseline: 4.8605x; 1.6736x over previous
//
#include <hip/hip_runtime.h>
#include <hip/hip_bf16.h>
#include <math.h>

#define NB 32
#define CK 512
#define C1 1024
#define CA 80
#define CQ 80
#define CQ2 160
#define TEN 400
#define TDE 2000
#define KDIM 1536
#define TPAD 448
#define TQP 2048

static constexpr float TEMP = 0.0005f;

typedef __attribute__((ext_vector_type(8))) short short8;
typedef __attribute__((ext_vector_type(4))) float f32x4;

__device__ inline short f2bf(float v) {
  __hip_bfloat16 h = __float2bfloat16(v);
  return *(short*)&h;
}
__device__ inline float bf2f(short s) {
  __hip_bfloat16 h = *(__hip_bfloat16*)&s;
  return __bfloat162float(h);
}

// ---------------------------------------------------------------------------
// Prepass: w1 f32[1024][1536] -> bf16 (layout unchanged)
// ---------------------------------------------------------------------------
__global__ __launch_bounds__(256) void cvt_w1_kernel(
    const float* __restrict__ w1, short* __restrict__ w1bf) {
  int i = blockIdx.x * 256 + threadIdx.x;
  if (i < C1 * KDIM) w1bf[i] = f2bf(w1[i]);
}

// ---------------------------------------------------------------------------
// Prepass: generic pad-convert f32 [M][K] -> bf16 [Mp][Kp] (zero pad)
// ---------------------------------------------------------------------------
__global__ __launch_bounds__(256) void cvt_pad_kernel(
    const float* __restrict__ src, short* __restrict__ dst,
    int M, int K, int Mp, int Kp) {
  int i = blockIdx.x * 256 + threadIdx.x;
  if (i >= Mp * Kp) return;
  int r = i / Kp, c = i - r * Kp;
  float v = (r < M && c < K) ? src[(size_t)r * K + c] : 0.f;
  dst[i] = f2bf(v);
}

// ---------------------------------------------------------------------------
// Prepass: keys im2col, t-major: BmatT[b][t][k] = keys[b][k/3][t + k%3 - 1]
// ---------------------------------------------------------------------------
__global__ __launch_bounds__(256) void im2col_kernel(
    const float* __restrict__ keys, short* __restrict__ BmatT) {
  const int t = blockIdx.x;
  const int b = blockIdx.y;
  const int tid = threadIdx.x;
  short* dst = BmatT + ((size_t)b * TPAD + t) * KDIM;
  #pragma unroll
  for (int i = 0; i < 6; ++i) {
    int k = tid + i * 256;
    int ci = k / 3;
    int dk = k - ci * 3;
    int ts = t + dk - 1;
    float v = (ts >= 0 && ts < TEN) ? keys[((size_t)b * CK + ci) * TEN + ts] : 0.f;
    dst[k] = f2bf(v);
  }
}

// ---------------------------------------------------------------------------
// Prepass: queries im2col: Bq[b][t][k], k in [0,256): k<240 -> q[b][k/3][t+k%3-1]
// ---------------------------------------------------------------------------
__global__ __launch_bounds__(256) void im2col_q_kernel(
    const float* __restrict__ queries, short* __restrict__ Bq) {
  const int t = blockIdx.x;          // 0..2047
  const int b = blockIdx.y;
  const int k = threadIdx.x;         // 0..255
  float v = 0.f;
  if (t < TDE && k < 240) {
    int ci = k / 3, dk = k - ci * 3, ts = t + dk - 1;
    v = (ts >= 0 && ts < TDE) ? queries[((size_t)b * CQ + ci) * TDE + ts] : 0.f;
  }
  Bq[((size_t)b * TQP + t) * 256 + k] = f2bf(v);
}

// ---------------------------------------------------------------------------
// Key conv1 via MFMA. Epilogue now stores k1 T-MAJOR: k1t[b][t][co] bf16 —
// this IS the B operand of the kconv2 GEMM (chaining, no transpose pass).
// ---------------------------------------------------------------------------
__global__ __launch_bounds__(256) void kconv1_mfma_kernel(
    const short* __restrict__ w1bf, const short* __restrict__ BmatT,
    const float* __restrict__ b1, short* __restrict__ k1t) {
  __shared__ short A_lds[2048];
  __shared__ short B_lds[2048];
  const int co0 = blockIdx.x * 64;
  const int t0  = blockIdx.y * 64;
  const int b   = blockIdx.z;
  const int tid = threadIdx.x;
  const int l = tid & 63, w = tid >> 6;
  const int srow = tid >> 2, sslot = tid & 3;

  const char* gA = (const char*)(w1bf + (size_t)(co0 + srow) * KDIM + sslot * 8);
  const char* gB = (const char*)(BmatT + ((size_t)b * TPAD + t0 + srow) * KDIM + sslot * 8);
  const int wbyte = (srow * 64 + sslot * 16) ^ ((srow & 7) << 4);

  const int kslot = l >> 4;
  const int arow = w * 16 + (l & 15);
  const int abyte = (arow * 64 + kslot * 16) ^ ((arow & 7) << 4);
  int bbyte[4];
  #pragma unroll
  for (int g = 0; g < 4; ++g) {
    int brow = g * 16 + (l & 15);
    bbyte[g] = (brow * 64 + kslot * 16) ^ ((brow & 7) << 4);
  }

  f32x4 acc[4];
  #pragma unroll
  for (int g = 0; g < 4; ++g) acc[g] = (f32x4){0.f, 0.f, 0.f, 0.f};

  for (int kt = 0; kt < KDIM / 32; ++kt) {
    uint4 av = *(const uint4*)(gA + (size_t)kt * 64);
    uint4 bv = *(const uint4*)(gB + (size_t)kt * 64);
    __syncthreads();
    *(uint4*)((char*)A_lds + wbyte) = av;
    *(uint4*)((char*)B_lds + wbyte) = bv;
    __syncthreads();
    short8 a = *(const short8*)((const char*)A_lds + abyte);
    #pragma unroll
    for (int g = 0; g < 4; ++g) {
      short8 bb = *(const short8*)((const char*)B_lds + bbyte[g]);
      acc[g] = __builtin_amdgcn_mfma_f32_16x16x32_bf16(a, bb, acc[g], 0, 0, 0);
    }
  }
  #pragma unroll
  for (int g = 0; g < 4; ++g) {
    int t = t0 + g * 16 + (l & 15);
    if (t < TEN) {
      #pragma unroll
      for (int r = 0; r < 4; ++r) {
        int co = co0 + w * 16 + kslot * 4 + r;
        float v = acc[g][r] + b1[co];
        k1t[((size_t)b * TPAD + t) * C1 + co] = f2bf(v > 0.f ? v : 0.f);
      }
    }
  }
}

// ---------------------------------------------------------------------------
// Generic small GEMM (proven R13 template).
// MODE 1: bf16 out[b][t][co]; MODE 2: f32 out[b][co][t].
// ---------------------------------------------------------------------------
template <int MODE, bool RELU>
__global__ __launch_bounds__(256) void qgemm_kernel(
    const short* __restrict__ A, const short* __restrict__ B,
    const float* __restrict__ bias, void* __restrict__ outv,
    int M, int Kpad, int kiters, int Nvalid, int outCols,
    size_t bBatchStride, size_t outBatchStride, int outLD) {
  __shared__ short A_lds[2048];
  __shared__ short B_lds[2048];
  const int co0 = blockIdx.x * 64;
  const int t0  = blockIdx.y * 64;
  const int b   = blockIdx.z;
  const int tid = threadIdx.x;
  const int l = tid & 63, w = tid >> 6;
  const int srow = tid >> 2, sslot = tid & 3;

  const short* gA = A + (size_t)(co0 + srow) * Kpad + sslot * 8;
  const short* gB = B + (size_t)b * bBatchStride + (size_t)(t0 + srow) * Kpad + sslot * 8;
  const int wbyte = (srow * 64 + sslot * 16) ^ ((srow & 7) << 4);

  const int kslot = l >> 4;
  const int arow = w * 16 + (l & 15);
  const int abyte = (arow * 64 + kslot * 16) ^ ((arow & 7) << 4);
  int bbyte[4];
  #pragma unroll
  for (int g = 0; g < 4; ++g) {
    int brow = g * 16 + (l & 15);
    bbyte[g] = (brow * 64 + kslot * 16) ^ ((brow & 7) << 4);
  }

  f32x4 acc[4];
  #pragma unroll
  for (int g = 0; g < 4; ++g) acc[g] = (f32x4){0.f, 0.f, 0.f, 0.f};

  for (int kt = 0; kt < kiters; ++kt) {
    uint4 av = *(const uint4*)(gA + kt * 32);
    uint4 bv = *(const uint4*)(gB + kt * 32);
    __syncthreads();
    *(uint4*)((char*)A_lds + wbyte) = av;
    *(uint4*)((char*)B_lds + wbyte) = bv;
    __syncthreads();
    short8 a = *(const short8*)((const char*)A_lds + abyte);
    #pragma unroll
    for (int g = 0; g < 4; ++g) {
      short8 bb = *(const short8*)((const char*)B_lds + bbyte[g]);
      acc[g] = __builtin_amdgcn_mfma_f32_16x16x32_bf16(a, bb, acc[g], 0, 0, 0);
    }
  }

  #pragma unroll
  for (int g = 0; g < 4; ++g) {
    int t = t0 + g * 16 + (l & 15);
    if (t >= Nvalid) continue;
    #pragma unroll
    for (int r = 0; r < 4; ++r) {
      int co = co0 + w * 16 + kslot * 4 + r;
      if (MODE == 1) {
        if (co < outCols) {
          float v = 0.f;
          if (co < M) {
            v = acc[g][r] + bias[co];
            if (RELU) v = v > 0.f ? v : 0.f;
          }
          ((short*)outv)[(size_t)b * outBatchStride + (size_t)t * outLD + co] = f2bf(v);
        }
      } else {  // MODE 2
        if (co < M) {
          float v = acc[g][r] + bias[co];
          if (RELU) v = v > 0.f ? v : 0.f;
          ((float*)outv)[(size_t)b * outBatchStride + (size_t)co * outLD + t] = v;
        }
      }
    }
  }
}

// ---------------------------------------------------------------------------
// Tiled attention (verbatim R13), f32 outputs
// ---------------------------------------------------------------------------
__global__ __launch_bounds__(256) void attn_kernel(
    const float* __restrict__ q3, const float* __restrict__ kfeat,
    const int* __restrict__ mask, float* __restrict__ out_attn,
    float* __restrict__ out_logp) {
  __shared__ float qT[80][16];
  __shared__ float lp[16][400];
  __shared__ float kLDS[80][64];
  __shared__ int mLDS[400];
  __shared__ float part[16][17];
  __shared__ float rowmax[16], rowinv[16];
  const int b = blockIdx.y;
  const int t0 = blockIdx.x * 16;
  const int tid = threadIdx.x;
  const int lane = tid & 63, w = tid >> 6;
  for (int idx = tid; idx < 80 * 16; idx += 256) {
    int c = idx >> 4, r = idx & 15;
    qT[c][r] = q3[((size_t)b * CA + c) * TDE + t0 + r];
  }
  for (int idx = tid; idx < 400; idx += 256) mLDS[idx] = mask[(size_t)b * TEN + idx];
  __syncthreads();
  for (int s0 = 0; s0 < TEN; s0 += 64) {
    for (int idx = tid; idx < 80 * 64; idx += 256) {
      int c = idx >> 6, j = idx & 63;
      int s = s0 + j;
      kLDS[c][j] = (s < TEN) ? kfeat[((size_t)b * CA + c) * TEN + s] : 0.f;
    }
    __syncthreads();
    float acc[4] = {0.f, 0.f, 0.f, 0.f};
    #pragma unroll 4
    for (int c = 0; c < 80; ++c) {
      float kv = kLDS[c][lane];
      #pragma unroll
      for (int i = 0; i < 4; ++i) {
        float d = qT[c][w * 4 + i] - kv;
        acc[i] += d * d;
      }
    }
    int s = s0 + lane;
    if (s < TEN) {
      #pragma unroll
      for (int i = 0; i < 4; ++i) lp[w * 4 + i][s] = acc[i];
    }
    __syncthreads();
  }
  for (int idx = tid; idx < 16 * 400; idx += 256) {
    int r = idx / 400, s = idx % 400;
    float v = mLDS[s] ? (-TEMP) * lp[r][s] : -INFINITY;
    lp[r][s] = v;
    out_logp[((size_t)(b * TDE + t0 + r)) * TEN + s] = v;
  }
  __syncthreads();
  const int g = tid >> 4;
  const int u = tid & 15;
  float pm = -INFINITY;
  for (int s = u; s < TEN; s += 16) pm = fmaxf(pm, lp[g][s]);
  part[g][u] = pm;
  __syncthreads();
  if (tid < 16) {
    float m = part[tid][0];
    #pragma unroll
    for (int k = 1; k < 16; ++k) m = fmaxf(m, part[tid][k]);
    rowmax[tid] = m;
  }
  __syncthreads();
  const float mg = rowmax[g];
  float ps = 0.f;
  for (int s = u; s < TEN; s += 16) {
    float v = lp[g][s];
    ps += (v != -INFINITY) ? __expf(v - mg) : 0.f;
  }
  part[g][u] = ps;
  __syncthreads();
  if (tid < 16) {
    float tot = 0.f;
    #pragma unroll
    for (int k = 0; k < 16; ++k) tot += part[tid][k];
    rowinv[tid] = 1.0f / tot;
  }
  __syncthreads();
  for (int idx = tid; idx < 16 * TEN; idx += 256) {
    int r = idx / TEN, s = idx % TEN;
    float v = lp[r][s];
    float e = (v != -INFINITY) ? __expf(v - rowmax[r]) * rowinv[r] : 0.f;
    out_attn[((size_t)(b * TDE + t0 + r)) * TEN + s] = e;
  }
}

extern "C" void kernel_launch(void* const* d_in, const int* in_sizes, int n_in,
                              void* d_out, int out_size, void* d_ws, size_t ws_size,
                              hipStream_t stream) {
  const float* queries = (const float*)d_in[0];
  const float* keys    = (const float*)d_in[1];
  const int*   mask    = (const int*)d_in[2];
  const float* kw1 = (const float*)d_in[3];
  const float* kb1 = (const float*)d_in[4];
  const float* kw2 = (const float*)d_in[5];
  const float* kb2 = (const float*)d_in[6];
  const float* qw1 = (const float*)d_in[7];
  const float* qb1 = (const float*)d_in[8];
  const float* qw2 = (const float*)d_in[9];
  const float* qb2 = (const float*)d_in[10];
  const float* qw3 = (const float*)d_in[11];
  const float* qb3 = (const float*)d_in[12];
  float* out = (float*)d_out;

  char* ws = (char*)d_ws;
  // ws overlays (stream-ordered; ws_size >= 86,016,000 proven):
  //  phase K: BmatT [0,44.04M) | w1bf [44.04M,47.19M) |
  //           k1t bf16 [32][448][1024] [47,185,920, 76,546,048) |
  //           w2bf [76,546,048, 76,808,192)
  //  phase Q: Bq [0,33.55M) | q1bf [33.55M,54.53M) | q2bf [54.53M,67.11M) |
  //           w1q/w2q/w3q [76,808,192, 76,972,032)
  //  phase A: q3 f32 [0,20.48M) | kfeat f32 [81.92M,86.02M)
  short* BmatT = (short*)ws;
  short* w1bf  = (short*)(ws + 44040192);
  short* k1t   = (short*)(ws + 47185920);
  short* w2bf  = (short*)(ws + 76546048);
  short* w1q   = (short*)(ws + 76808192);
  short* w2q   = (short*)(ws + 76906496);
  short* w3q   = (short*)(ws + 76947456);
  short* Bq    = (short*)ws;
  short* q1bf  = (short*)(ws + 33554432);
  short* q2bf  = (short*)(ws + 54525952);
  float* q3    = (float*)ws;
  float* kfeat = (float*)(ws + 81920000);

  const long long HALF = 25600000LL;
  float* out_attn = out;
  float* out_logp = out + HALF;

  // --- key path (all MFMA) ---
  cvt_w1_kernel<<<dim3((C1 * KDIM + 255) / 256), dim3(256), 0, stream>>>(kw1, w1bf);
  im2col_kernel<<<dim3(TEN, NB), dim3(256), 0, stream>>>(keys, BmatT);
  kconv1_mfma_kernel<<<dim3(16, 7, NB), dim3(256), 0, stream>>>(w1bf, BmatT, kb1, k1t);
  cvt_pad_kernel<<<dim3((128 * 1024 + 255) / 256), dim3(256), 0, stream>>>(
      kw2, w2bf, CA, C1, 128, C1);
  qgemm_kernel<2, false><<<dim3(2, 7, NB), dim3(256), 0, stream>>>(
      w2bf, k1t, kb2, kfeat, CA, C1, 32, TEN, CA,
      (size_t)TPAD * C1, (size_t)CA * TEN, TEN);

  // --- query path (MFMA chain, verbatim R13) ---
  cvt_pad_kernel<<<dim3((192 * 256 + 255) / 256), dim3(256), 0, stream>>>(
      qw1, w1q, CQ2, 240, 192, 256);
  cvt_pad_kernel<<<dim3((128 * 160 + 255) / 256), dim3(256), 0, stream>>>(
      qw2, w2q, CA, CQ2, 128, 160);
  cvt_pad_kernel<<<dim3((128 * 96 + 255) / 256), dim3(256), 0, stream>>>(
      qw3, w3q, CA, CQ, 128, 96);
  im2col_q_kernel<<<dim3(TQP, NB), dim3(256), 0, stream>>>(queries, Bq);
  qgemm_kernel<1, true><<<dim3(3, TQP / 64, NB), dim3(256), 0, stream>>>(
      w1q, Bq, qb1, q1bf, CQ2, 256, 8, TDE, 160,
      (size_t)TQP * 256, (size_t)TQP * 160, 160);
  qgemm_kernel<1, true><<<dim3(2, TQP / 64, NB), dim3(256), 0, stream>>>(
      w2q, q1bf, qb2, q2bf, CA, 160, 5, TDE, 96,
      (size_t)TQP * 160, (size_t)TQP * 96, 96);
  qgemm_kernel<2, false><<<dim3(2, TQP / 64, NB), dim3(256), 0, stream>>>(
      w3q, q2bf, qb3, q3, CA, 96, 3, TDE, 80,
      (size_t)TQP * 96, (size_t)CA * TDE, TDE);

  // --- attention ---
  attn_kernel<<<dim3(125, NB), dim3(256), 0, stream>>>(q3, kfeat, mask,
                                                       out_attn, out_logp);
}

// Round 15
// 436.300 us; speedup vs baseline: 6.8728x; 1.4140x over previous
//
#include <hip/hip_runtime.h>
#include <hip/hip_bf16.h>
#include <math.h>

#define NB 32
#define CK 512
#define C1 1024
#define CA 80
#define CQ 80
#define CQ2 160
#define TEN 400
#define TDE 2000
#define KDIM 1536
#define TPAD 448
#define TQP 2048

static constexpr float TEMP = 0.0005f;

typedef __attribute__((ext_vector_type(8))) short short8;
typedef __attribute__((ext_vector_type(4))) float f32x4;

__device__ inline short f2bf(float v) {
  __hip_bfloat16 h = __float2bfloat16(v);
  return *(short*)&h;
}
__device__ inline float bf2f(short s) {
  __hip_bfloat16 h = *(__hip_bfloat16*)&s;
  return __bfloat162float(h);
}

// ---------------------------------------------------------------------------
// Prepass: w1 f32[1024][1536] -> bf16
// ---------------------------------------------------------------------------
__global__ __launch_bounds__(256) void cvt_w1_kernel(
    const float* __restrict__ w1, short* __restrict__ w1bf) {
  int i = blockIdx.x * 256 + threadIdx.x;
  if (i < C1 * KDIM) w1bf[i] = f2bf(w1[i]);
}

// ---------------------------------------------------------------------------
// Prepass: generic pad-convert f32 [M][K] -> bf16 [Mp][Kp]
// ---------------------------------------------------------------------------
__global__ __launch_bounds__(256) void cvt_pad_kernel(
    const float* __restrict__ src, short* __restrict__ dst,
    int M, int K, int Mp, int Kp) {
  int i = blockIdx.x * 256 + threadIdx.x;
  if (i >= Mp * Kp) return;
  int r = i / Kp, c = i - r * Kp;
  float v = (r < M && c < K) ? src[(size_t)r * K + c] : 0.f;
  dst[i] = f2bf(v);
}

// ---------------------------------------------------------------------------
// Prepass: keys im2col (t-major)
// ---------------------------------------------------------------------------
__global__ __launch_bounds__(256) void im2col_kernel(
    const float* __restrict__ keys, short* __restrict__ BmatT) {
  const int t = blockIdx.x;
  const int b = blockIdx.y;
  const int tid = threadIdx.x;
  short* dst = BmatT + ((size_t)b * TPAD + t) * KDIM;
  #pragma unroll
  for (int i = 0; i < 6; ++i) {
    int k = tid + i * 256;
    int ci = k / 3;
    int dk = k - ci * 3;
    int ts = t + dk - 1;
    float v = (ts >= 0 && ts < TEN) ? keys[((size_t)b * CK + ci) * TEN + ts] : 0.f;
    dst[k] = f2bf(v);
  }
}

// ---------------------------------------------------------------------------
// Prepass: queries im2col
// ---------------------------------------------------------------------------
__global__ __launch_bounds__(256) void im2col_q_kernel(
    const float* __restrict__ queries, short* __restrict__ Bq) {
  const int t = blockIdx.x;
  const int b = blockIdx.y;
  const int k = threadIdx.x;
  float v = 0.f;
  if (t < TDE && k < 240) {
    int ci = k / 3, dk = k - ci * 3, ts = t + dk - 1;
    v = (ts >= 0 && ts < TDE) ? queries[((size_t)b * CQ + ci) * TDE + ts] : 0.f;
  }
  Bq[((size_t)b * TQP + t) * 256 + k] = f2bf(v);
}

// ---------------------------------------------------------------------------
// Key conv1 via MFMA -> k1t[b][t][co] bf16 (verbatim R14)
// ---------------------------------------------------------------------------
__global__ __launch_bounds__(256) void kconv1_mfma_kernel(
    const short* __restrict__ w1bf, const short* __restrict__ BmatT,
    const float* __restrict__ b1, short* __restrict__ k1t) {
  __shared__ short A_lds[2048];
  __shared__ short B_lds[2048];
  const int co0 = blockIdx.x * 64;
  const int t0  = blockIdx.y * 64;
  const int b   = blockIdx.z;
  const int tid = threadIdx.x;
  const int l = tid & 63, w = tid >> 6;
  const int srow = tid >> 2, sslot = tid & 3;

  const char* gA = (const char*)(w1bf + (size_t)(co0 + srow) * KDIM + sslot * 8);
  const char* gB = (const char*)(BmatT + ((size_t)b * TPAD + t0 + srow) * KDIM + sslot * 8);
  const int wbyte = (srow * 64 + sslot * 16) ^ ((srow & 7) << 4);

  const int kslot = l >> 4;
  const int arow = w * 16 + (l & 15);
  const int abyte = (arow * 64 + kslot * 16) ^ ((arow & 7) << 4);
  int bbyte[4];
  #pragma unroll
  for (int g = 0; g < 4; ++g) {
    int brow = g * 16 + (l & 15);
    bbyte[g] = (brow * 64 + kslot * 16) ^ ((brow & 7) << 4);
  }

  f32x4 acc[4];
  #pragma unroll
  for (int g = 0; g < 4; ++g) acc[g] = (f32x4){0.f, 0.f, 0.f, 0.f};

  for (int kt = 0; kt < KDIM / 32; ++kt) {
    uint4 av = *(const uint4*)(gA + (size_t)kt * 64);
    uint4 bv = *(const uint4*)(gB + (size_t)kt * 64);
    __syncthreads();
    *(uint4*)((char*)A_lds + wbyte) = av;
    *(uint4*)((char*)B_lds + wbyte) = bv;
    __syncthreads();
    short8 a = *(const short8*)((const char*)A_lds + abyte);
    #pragma unroll
    for (int g = 0; g < 4; ++g) {
      short8 bb = *(const short8*)((const char*)B_lds + bbyte[g]);
      acc[g] = __builtin_amdgcn_mfma_f32_16x16x32_bf16(a, bb, acc[g], 0, 0, 0);
    }
  }
  #pragma unroll
  for (int g = 0; g < 4; ++g) {
    int t = t0 + g * 16 + (l & 15);
    if (t < TEN) {
      #pragma unroll
      for (int r = 0; r < 4; ++r) {
        int co = co0 + w * 16 + kslot * 4 + r;
        float v = acc[g][r] + b1[co];
        k1t[((size_t)b * TPAD + t) * C1 + co] = f2bf(v > 0.f ? v : 0.f);
      }
    }
  }
}

// ---------------------------------------------------------------------------
// Generic small GEMM (proven template). MODE 1: bf16 [b][t][co];
// MODE 2: f32 [b][co][t].
// ---------------------------------------------------------------------------
template <int MODE, bool RELU>
__global__ __launch_bounds__(256) void qgemm_kernel(
    const short* __restrict__ A, const short* __restrict__ B,
    const float* __restrict__ bias, void* __restrict__ outv,
    int M, int Kpad, int kiters, int Nvalid, int outCols,
    size_t bBatchStride, size_t outBatchStride, int outLD) {
  __shared__ short A_lds[2048];
  __shared__ short B_lds[2048];
  const int co0 = blockIdx.x * 64;
  const int t0  = blockIdx.y * 64;
  const int b   = blockIdx.z;
  const int tid = threadIdx.x;
  const int l = tid & 63, w = tid >> 6;
  const int srow = tid >> 2, sslot = tid & 3;

  const short* gA = A + (size_t)(co0 + srow) * Kpad + sslot * 8;
  const short* gB = B + (size_t)b * bBatchStride + (size_t)(t0 + srow) * Kpad + sslot * 8;
  const int wbyte = (srow * 64 + sslot * 16) ^ ((srow & 7) << 4);

  const int kslot = l >> 4;
  const int arow = w * 16 + (l & 15);
  const int abyte = (arow * 64 + kslot * 16) ^ ((arow & 7) << 4);
  int bbyte[4];
  #pragma unroll
  for (int g = 0; g < 4; ++g) {
    int brow = g * 16 + (l & 15);
    bbyte[g] = (brow * 64 + kslot * 16) ^ ((brow & 7) << 4);
  }

  f32x4 acc[4];
  #pragma unroll
  for (int g = 0; g < 4; ++g) acc[g] = (f32x4){0.f, 0.f, 0.f, 0.f};

  for (int kt = 0; kt < kiters; ++kt) {
    uint4 av = *(const uint4*)(gA + kt * 32);
    uint4 bv = *(const uint4*)(gB + kt * 32);
    __syncthreads();
    *(uint4*)((char*)A_lds + wbyte) = av;
    *(uint4*)((char*)B_lds + wbyte) = bv;
    __syncthreads();
    short8 a = *(const short8*)((const char*)A_lds + abyte);
    #pragma unroll
    for (int g = 0; g < 4; ++g) {
      short8 bb = *(const short8*)((const char*)B_lds + bbyte[g]);
      acc[g] = __builtin_amdgcn_mfma_f32_16x16x32_bf16(a, bb, acc[g], 0, 0, 0);
    }
  }

  #pragma unroll
  for (int g = 0; g < 4; ++g) {
    int t = t0 + g * 16 + (l & 15);
    if (t >= Nvalid) continue;
    #pragma unroll
    for (int r = 0; r < 4; ++r) {
      int co = co0 + w * 16 + kslot * 4 + r;
      if (MODE == 1) {
        if (co < outCols) {
          float v = 0.f;
          if (co < M) {
            v = acc[g][r] + bias[co];
            if (RELU) v = v > 0.f ? v : 0.f;
          }
          ((short*)outv)[(size_t)b * outBatchStride + (size_t)t * outLD + co] = f2bf(v);
        }
      } else {
        if (co < M) {
          float v = acc[g][r] + bias[co];
          if (RELU) v = v > 0.f ? v : 0.f;
          ((float*)outv)[(size_t)b * outBatchStride + (size_t)co * outLD + t] = v;
        }
      }
    }
  }
}

// ---------------------------------------------------------------------------
// Attn prep: q3 f32 [b][80][2000] -> qA bf16 [b][2048][96] + q2 norms f32
// ---------------------------------------------------------------------------
__global__ __launch_bounds__(256) void prep_attn_q_kernel(
    const float* __restrict__ q3, short* __restrict__ qA,
    float* __restrict__ q2) {
  __shared__ float sm[80][64];
  const int b = blockIdx.y;
  const int t0 = blockIdx.x * 64;          // 32 tiles -> 2048
  const int tid = threadIdx.x;
  for (int idx = tid; idx < 80 * 64; idx += 256) {
    int a = idx >> 6, j = idx & 63;
    int t = t0 + j;
    sm[a][j] = (t < TDE) ? q3[((size_t)b * CA + a) * TDE + t] : 0.f;
  }
  __syncthreads();
  if (tid < 64) {
    float ss = 0.f;
    #pragma unroll 8
    for (int a = 0; a < 80; ++a) { float v = sm[a][tid]; ss += v * v; }
    q2[(size_t)b * TQP + t0 + tid] = ss;
  }
  for (int idx = tid; idx < 64 * 96; idx += 256) {
    int j = idx / 96, k = idx - j * 96;
    float v = (k < 80) ? sm[k][j] : 0.f;
    qA[((size_t)b * TQP + t0 + j) * 96 + k] = f2bf(v);
  }
}

// ---------------------------------------------------------------------------
// Attn prep: kfeat f32 [b][80][400] -> kB bf16 [b][448][96] + k2 norms f32
// ---------------------------------------------------------------------------
__global__ __launch_bounds__(256) void prep_attn_k_kernel(
    const float* __restrict__ kfeat, short* __restrict__ kB,
    float* __restrict__ k2) {
  __shared__ float sm[80][64];
  const int b = blockIdx.y;
  const int s0 = blockIdx.x * 64;          // 7 tiles -> 448
  const int tid = threadIdx.x;
  for (int idx = tid; idx < 80 * 64; idx += 256) {
    int a = idx >> 6, j = idx & 63;
    int s = s0 + j;
    sm[a][j] = (s < TEN) ? kfeat[((size_t)b * CA + a) * TEN + s] : 0.f;
  }
  __syncthreads();
  if (tid < 64) {
    float ss = 0.f;
    #pragma unroll 8
    for (int a = 0; a < 80; ++a) { float v = sm[a][tid]; ss += v * v; }
    k2[(size_t)b * TPAD + s0 + tid] = ss;
  }
  for (int idx = tid; idx < 64 * 96; idx += 256) {
    int j = idx / 96, k = idx - j * 96;
    float v = (k < 80) ? sm[k][j] : 0.f;
    kB[((size_t)b * TPAD + s0 + j) * 96 + k] = f2bf(v);
  }
}

// ---------------------------------------------------------------------------
// QK^T via MFMA + fused logp epilogue: lp = -T*(q2+k2-2*qk), masked.
// Writes out_logp directly (it IS output 1).
// ---------------------------------------------------------------------------
__global__ __launch_bounds__(256) void qkt_mfma_kernel(
    const short* __restrict__ qA, const short* __restrict__ kB,
    const float* __restrict__ q2, const float* __restrict__ k2,
    const int* __restrict__ mask, float* __restrict__ out_logp) {
  __shared__ short A_lds[2048];
  __shared__ short B_lds[2048];
  const int t0 = blockIdx.x * 64;
  const int s0 = blockIdx.y * 64;
  const int b  = blockIdx.z;
  const int tid = threadIdx.x;
  const int l = tid & 63, w = tid >> 6;
  const int srow = tid >> 2, sslot = tid & 3;

  const short* gA = qA + ((size_t)b * TQP + t0 + srow) * 96 + sslot * 8;
  const short* gB = kB + ((size_t)b * TPAD + s0 + srow) * 96 + sslot * 8;
  const int wbyte = (srow * 64 + sslot * 16) ^ ((srow & 7) << 4);

  const int kslot = l >> 4;
  const int arow = w * 16 + (l & 15);
  const int abyte = (arow * 64 + kslot * 16) ^ ((arow & 7) << 4);
  int bbyte[4];
  #pragma unroll
  for (int g = 0; g < 4; ++g) {
    int brow = g * 16 + (l & 15);
    bbyte[g] = (brow * 64 + kslot * 16) ^ ((brow & 7) << 4);
  }

  f32x4 acc[4];
  #pragma unroll
  for (int g = 0; g < 4; ++g) acc[g] = (f32x4){0.f, 0.f, 0.f, 0.f};

  #pragma unroll
  for (int kt = 0; kt < 3; ++kt) {
    uint4 av = *(const uint4*)(gA + kt * 32);
    uint4 bv = *(const uint4*)(gB + kt * 32);
    __syncthreads();
    *(uint4*)((char*)A_lds + wbyte) = av;
    *(uint4*)((char*)B_lds + wbyte) = bv;
    __syncthreads();
    short8 a = *(const short8*)((const char*)A_lds + abyte);
    #pragma unroll
    for (int g = 0; g < 4; ++g) {
      short8 bb = *(const short8*)((const char*)B_lds + bbyte[g]);
      acc[g] = __builtin_amdgcn_mfma_f32_16x16x32_bf16(a, bb, acc[g], 0, 0, 0);
    }
  }

  const int trow = t0 + w * 16 + kslot * 4;
  float q2v[4];
  #pragma unroll
  for (int r = 0; r < 4; ++r)
    q2v[r] = (trow + r < TDE) ? q2[(size_t)b * TQP + trow + r] : 0.f;

  #pragma unroll
  for (int g = 0; g < 4; ++g) {
    int s = s0 + g * 16 + (l & 15);
    if (s >= TEN) continue;
    const int mk = mask[(size_t)b * TEN + s];
    const float k2v = k2[(size_t)b * TPAD + s];
    #pragma unroll
    for (int r = 0; r < 4; ++r) {
      int t = trow + r;
      if (t >= TDE) continue;
      float lp = mk ? (-TEMP) * (q2v[r] + k2v - 2.f * acc[g][r]) : -INFINITY;
      out_logp[((size_t)(b * TDE + t)) * TEN + s] = lp;
    }
  }
}

// ---------------------------------------------------------------------------
// Softmax pass: reads logp from d_out, writes attn. Memory-bound streaming.
// ---------------------------------------------------------------------------
__global__ __launch_bounds__(256) void softmax_kernel(
    const float* __restrict__ out_logp, float* __restrict__ out_attn) {
  __shared__ float lp[16][400];
  __shared__ float part[16][17];
  __shared__ float rowmax[16], rowinv[16];
  const int b = blockIdx.y;
  const int t0 = blockIdx.x * 16;
  const int tid = threadIdx.x;
  for (int idx = tid; idx < 16 * 400; idx += 256) {
    int r = idx / 400, s = idx - r * 400;
    lp[r][s] = out_logp[((size_t)(b * TDE + t0 + r)) * TEN + s];
  }
  __syncthreads();
  const int g = tid >> 4;
  const int u = tid & 15;
  float pm = -INFINITY;
  for (int s = u; s < TEN; s += 16) pm = fmaxf(pm, lp[g][s]);
  part[g][u] = pm;
  __syncthreads();
  if (tid < 16) {
    float m = part[tid][0];
    #pragma unroll
    for (int k = 1; k < 16; ++k) m = fmaxf(m, part[tid][k]);
    rowmax[tid] = m;
  }
  __syncthreads();
  const float mg = rowmax[g];
  float ps = 0.f;
  for (int s = u; s < TEN; s += 16) {
    float v = lp[g][s];
    ps += (v != -INFINITY) ? __expf(v - mg) : 0.f;
  }
  part[g][u] = ps;
  __syncthreads();
  if (tid < 16) {
    float tot = 0.f;
    #pragma unroll
    for (int k = 0; k < 16; ++k) tot += part[tid][k];
    rowinv[tid] = 1.0f / tot;
  }
  __syncthreads();
  for (int idx = tid; idx < 16 * TEN; idx += 256) {
    int r = idx / TEN, s = idx - r * TEN;
    float v = lp[r][s];
    float e = (v != -INFINITY) ? __expf(v - rowmax[r]) * rowinv[r] : 0.f;
    out_attn[((size_t)(b * TDE + t0 + r)) * TEN + s] = e;
  }
}

extern "C" void kernel_launch(void* const* d_in, const int* in_sizes, int n_in,
                              void* d_out, int out_size, void* d_ws, size_t ws_size,
                              hipStream_t stream) {
  const float* queries = (const float*)d_in[0];
  const float* keys    = (const float*)d_in[1];
  const int*   mask    = (const int*)d_in[2];
  const float* kw1 = (const float*)d_in[3];
  const float* kb1 = (const float*)d_in[4];
  const float* kw2 = (const float*)d_in[5];
  const float* kb2 = (const float*)d_in[6];
  const float* qw1 = (const float*)d_in[7];
  const float* qb1 = (const float*)d_in[8];
  const float* qw2 = (const float*)d_in[9];
  const float* qb2 = (const float*)d_in[10];
  const float* qw3 = (const float*)d_in[11];
  const float* qb3 = (const float*)d_in[12];
  float* out = (float*)d_out;

  char* ws = (char*)d_ws;
  // ws overlays (stream-ordered; ws_size >= 86,016,000 proven):
  //  K: BmatT [0,44.04M) | w1bf [44.04M,47.19M) | k1t [47.19M,76.55M) |
  //     w2bf [76.55M,76.81M) | kfeat [81.92M,86.02M)
  //  Q: Bq [0,33.55M) | q1bf [33.55M,54.53M) | q2bf [54.53M,67.11M) |
  //     w1q/w2q/w3q [76.81M,76.97M)
  //  A: q3 [0,20.48M) | qA [20.48M,33.06M) | q2 [33.06M,33.33M) (dead Bq) |
  //     kB [47.19M,49.94M) | k2 [49.94M,50.00M) (dead k1t)
  short* BmatT = (short*)ws;
  short* w1bf  = (short*)(ws + 44040192);
  short* k1t   = (short*)(ws + 47185920);
  short* w2bf  = (short*)(ws + 76546048);
  short* w1q   = (short*)(ws + 76808192);
  short* w2q   = (short*)(ws + 76906496);
  short* w3q   = (short*)(ws + 76947456);
  short* Bq    = (short*)ws;
  short* q1bf  = (short*)(ws + 33554432);
  short* q2bf  = (short*)(ws + 54525952);
  float* q3    = (float*)ws;
  short* qA    = (short*)(ws + 20480000);
  float* q2n   = (float*)(ws + 33062912);
  short* kB    = (short*)(ws + 47185920);
  float* k2n   = (float*)(ws + 49938432);
  float* kfeat = (float*)(ws + 81920000);

  const long long HALF = 25600000LL;
  float* out_attn = out;
  float* out_logp = out + HALF;

  // --- key path (all MFMA) ---
  cvt_w1_kernel<<<dim3((C1 * KDIM + 255) / 256), dim3(256), 0, stream>>>(kw1, w1bf);
  im2col_kernel<<<dim3(TEN, NB), dim3(256), 0, stream>>>(keys, BmatT);
  kconv1_mfma_kernel<<<dim3(16, 7, NB), dim3(256), 0, stream>>>(w1bf, BmatT, kb1, k1t);
  cvt_pad_kernel<<<dim3((128 * 1024 + 255) / 256), dim3(256), 0, stream>>>(
      kw2, w2bf, CA, C1, 128, C1);
  qgemm_kernel<2, false><<<dim3(2, 7, NB), dim3(256), 0, stream>>>(
      w2bf, k1t, kb2, kfeat, CA, C1, 32, TEN, CA,
      (size_t)TPAD * C1, (size_t)CA * TEN, TEN);

  // --- query path (MFMA chain) ---
  cvt_pad_kernel<<<dim3((192 * 256 + 255) / 256), dim3(256), 0, stream>>>(
      qw1, w1q, CQ2, 240, 192, 256);
  cvt_pad_kernel<<<dim3((128 * 160 + 255) / 256), dim3(256), 0, stream>>>(
      qw2, w2q, CA, CQ2, 128, 160);
  cvt_pad_kernel<<<dim3((128 * 96 + 255) / 256), dim3(256), 0, stream>>>(
      qw3, w3q, CA, CQ, 128, 96);
  im2col_q_kernel<<<dim3(TQP, NB), dim3(256), 0, stream>>>(queries, Bq);
  qgemm_kernel<1, true><<<dim3(3, TQP / 64, NB), dim3(256), 0, stream>>>(
      w1q, Bq, qb1, q1bf, CQ2, 256, 8, TDE, 160,
      (size_t)TQP * 256, (size_t)TQP * 160, 160);
  qgemm_kernel<1, true><<<dim3(2, TQP / 64, NB), dim3(256), 0, stream>>>(
      w2q, q1bf, qb2, q2bf, CA, 160, 5, TDE, 96,
      (size_t)TQP * 160, (size_t)TQP * 96, 96);
  qgemm_kernel<2, false><<<dim3(2, TQP / 64, NB), dim3(256), 0, stream>>>(
      w3q, q2bf, qb3, q3, CA, 96, 3, TDE, 80,
      (size_t)TQP * 96, (size_t)CA * TDE, TDE);

  // --- attention: prep -> MFMA QK^T (+fused logp) -> softmax ---
  prep_attn_q_kernel<<<dim3(TQP / 64, NB), dim3(256), 0, stream>>>(q3, qA, q2n);
  prep_attn_k_kernel<<<dim3(TPAD / 64, NB), dim3(256), 0, stream>>>(kfeat, kB, k2n);
  qkt_mfma_kernel<<<dim3(TQP / 64, TPAD / 64, NB), dim3(256), 0, stream>>>(
      qA, kB, q2n, k2n, mask, out_logp);
  softmax_kernel<<<dim3(125, NB), dim3(256), 0, stream>>>(out_logp, out_attn);
}